// Round 5
// baseline (269.706 us; speedup 1.0000x reference)
//
#include <hip/hip_runtime.h>

// FixedSparseMultiHead: B=2, S=2048, D=1024, H=16, Hd=64, local band ±102.
// Round 5: gemm_core rework (attn unchanged from round 4):
//   - LDS chunk layout [kh][row][8elem] -> fragment ds_read_b128 is lane-linear
//     (zero bank conflicts); staging lane map swapped to match (global footprint
//     identical, still 16B/lane gload_lds).
//   - depth-3 counted-vmcnt pipeline: 3 LDS buffers, stage t+3 after a
//     read-complete barrier, consume waits vmcnt(8) (T4; never drain to 0 in
//     the main loop). Raw s_barrier + explicit lgkmcnt(0) make overwrite safe.
// Pipeline: split5 -> gemm_qkv (Q,K bf16 [B,H,S,64]; V^T bf16 [B,H,64,2176])
//           -> attn_mfma -> gemm_out. Fallback fp32 path if ws_size < 80MB.

#define SEQ    2048
#define DMODEL 1024
#define NHEAD  16
#define HDIM   64
#define HALFW  102
#define BWMAX  240
#define VTS    2176    // padded V^T row stride (zeros beyond SEQ)

typedef unsigned short u16;
typedef __attribute__((ext_vector_type(8))) short bf16x8;
typedef __attribute__((ext_vector_type(4))) float f32x4;

#define VMW8()  asm volatile("s_waitcnt vmcnt(8)" ::: "memory")
#define VMW4()  asm volatile("s_waitcnt vmcnt(4)" ::: "memory")
#define VMW0()  asm volatile("s_waitcnt vmcnt(0)" ::: "memory")
#define LGKM0() asm volatile("s_waitcnt lgkmcnt(0)" ::: "memory")
#define BARR()  __builtin_amdgcn_s_barrier()
#define CFENCE() asm volatile("" ::: "memory")

__device__ __forceinline__ u16 f2bf(float f) {
    unsigned u = __builtin_bit_cast(unsigned, f);
    unsigned r = (u + 0x7fffu + ((u >> 16) & 1u)) >> 16;   // RNE
    return (u16)r;
}
__device__ __forceinline__ float bf2f(u16 u) {
    return __builtin_bit_cast(float, ((unsigned)u) << 16);
}

__device__ __forceinline__ void gload16(const void* g, void* l) {
    __builtin_amdgcn_global_load_lds(
        (const __attribute__((address_space(1))) void*)g,
        (__attribute__((address_space(3))) void*)l, 16, 0, 0);
}

// ---------------------------------------------------------------------------
// split: fp32 -> (hi,lo) bf16.  y=0: x (4M elems); y=1..4: Wq/Wk/Wv/Wo (1M).
// ---------------------------------------------------------------------------
__global__ __launch_bounds__(256) void split5(
    const float* __restrict__ x,  const float* __restrict__ wq,
    const float* __restrict__ wk, const float* __restrict__ wv,
    const float* __restrict__ wo,
    u16* __restrict__ xhi, u16* __restrict__ xlo, u16* __restrict__ wbase)
{
    const int y = blockIdx.y;
    const float* src; u16* hi; u16* lo; int nblk;
    switch (y) {
      case 0:  src = x;  hi = xhi;             lo = xlo;             nblk = 4096; break;
      case 1:  src = wq; hi = wbase;           lo = wbase + 1048576; nblk = 1024; break;
      case 2:  src = wk; hi = wbase + 2097152; lo = wbase + 3145728; nblk = 1024; break;
      case 3:  src = wv; hi = wbase + 4194304; lo = wbase + 5242880; nblk = 1024; break;
      default: src = wo; hi = wbase + 6291456; lo = wbase + 7340032; nblk = 1024; break;
    }
    const int bx = blockIdx.x;
    if (bx >= nblk) return;
    const int i = (bx * 256 + threadIdx.x) * 4;
    const float4 v = *(const float4*)(src + i);
    ushort4 h, l;
    h.x = f2bf(v.x); l.x = f2bf(v.x - bf2f(h.x));
    h.y = f2bf(v.y); l.y = f2bf(v.y - bf2f(h.y));
    h.z = f2bf(v.z); l.z = f2bf(v.z - bf2f(h.z));
    h.w = f2bf(v.w); l.w = f2bf(v.w - bf2f(h.w));
    *(ushort4*)(hi + i) = h;
    *(ushort4*)(lo + i) = l;
}

// ---------------------------------------------------------------------------
// MFMA GEMM core: C[128x128] += 3 passes (Ahi*Bhi, Alo*Bhi, Ahi*Blo), K=1024,
// BK=32. 256 thr = 4 waves (2x2 of 64x64).
// LDS: 3 buffers, each 8 chunks of [4 khalves][16 rows][8 elems] (chunk=1KB).
//   staging: lane ln loads global(row = c*16 + (ln&15), col = k0 + (ln>>4)*8)
//            -> LDS chunk_base + ln*16B (gload_lds linear write).
//   frag read: lane ln reads chunk_base + ln*16B -> stride-1, conflict-free.
// Schedule: stage(0..2); loop t: { vmcnt(8); barrier; ds_read+16 MFMA;
//   lgkmcnt(0); barrier; stage(t+3) }.  Tail drains vmcnt 8/4/0.
// ---------------------------------------------------------------------------
__device__ __forceinline__ void gemm_core(
    const u16* __restrict__ Ahi, const u16* __restrict__ Alo,
    const u16* __restrict__ Bhi, const u16* __restrict__ Blo,
    int m0, int n0, u16 (*sA)[4096], u16 (*sB)[4096], f32x4 acc[4][4])
{
    const int tid = threadIdx.x, ln = tid & 63, wave = tid >> 6;
    const int wm = wave >> 1, wn = wave & 1;
    const int srow = ln & 15, scol = (ln >> 4) * 8;

#pragma unroll
    for (int fm = 0; fm < 4; ++fm)
#pragma unroll
        for (int fn = 0; fn < 4; ++fn) acc[fm][fn] = (f32x4){0.f, 0.f, 0.f, 0.f};

    auto stage = [&](int s, u16* dA, u16* dB) {
        const u16* Ap = (s >= 32 && s < 64) ? Alo : Ahi;
        const u16* Bp = (s >= 64) ? Blo : Bhi;
        const int k0 = (s & 31) << 5;
#pragma unroll
        for (int c = wave; c < 8; c += 4) {
            gload16(Ap + (size_t)(m0 + c * 16 + srow) * 1024 + k0 + scol, dA + c * 512);
            gload16(Bp + (size_t)(n0 + c * 16 + srow) * 1024 + k0 + scol, dB + c * 512);
        }
    };

    auto compute = [&](const u16* As, const u16* Bs) {
        bf16x8 a[4], b[4];
#pragma unroll
        for (int f = 0; f < 4; ++f) {
            a[f] = *(const bf16x8*)(As + (wm * 4 + f) * 512 + (size_t)ln * 8);
            b[f] = *(const bf16x8*)(Bs + (wn * 4 + f) * 512 + (size_t)ln * 8);
        }
#pragma unroll
        for (int fm = 0; fm < 4; ++fm)
#pragma unroll
            for (int fn = 0; fn < 4; ++fn)
                acc[fm][fn] = __builtin_amdgcn_mfma_f32_16x16x32_bf16(
                    a[fm], b[fn], acc[fm][fn], 0, 0, 0);
    };

    stage(0, sA[0], sB[0]);
    stage(1, sA[1], sB[1]);
    stage(2, sA[2], sB[2]);

    for (int t = 0; t < 93; t += 3) {
#pragma unroll
        for (int u = 0; u < 3; ++u) {
            VMW8();            // own 4 loads of buf u's stage done (8 newer allowed)
            BARR();            // -> all waves' loads for buf u landed
            CFENCE();
            compute(sA[u], sB[u]);
            LGKM0();           // LDS reads of buf u complete before we allow overwrite
            BARR();            // -> all waves done reading buf u
            stage(t + u + 3, sA[u], sB[u]);
        }
    }
    VMW8(); BARR(); CFENCE(); compute(sA[0], sB[0]);   // t=93
    VMW4(); BARR(); CFENCE(); compute(sA[1], sB[1]);   // t=94
    VMW0(); BARR(); CFENCE(); compute(sA[2], sB[2]);   // t=95
}

// ---------------------------------------------------------------------------
// Fused Q/K/V^T projection. y=0: Q bf16 [B,H,S,64]; y=1: K bf16 [B,H,S,64];
// y=2: V^T bf16 [B,H,64,VTS] via swapped operands (A=Wv, B=x).
// ---------------------------------------------------------------------------
__global__ __launch_bounds__(256) void gemm_qkv(
    const u16* __restrict__ xhi, const u16* __restrict__ xlo,
    const u16* __restrict__ wbase,
    const float* __restrict__ bq, const float* __restrict__ bk,
    const float* __restrict__ bvv,
    u16* __restrict__ Qo, u16* __restrict__ Ko, u16* __restrict__ VTo)
{
    __shared__ u16 sA[3][4096], sB[3][4096];   // 48 KB -> 3 blocks/CU
    const int y = blockIdx.y;
    const u16* Whi = wbase + (size_t)y * 2097152;
    const u16* Wlo = Whi + 1048576;

    const int bx = blockIdx.x;
    int m0, n0;
    if (y == 2) { m0 = (bx & 7) * 128; n0 = (bx >> 3) * 128; }          // m over D, n over 4096
    else { m0 = ((bx & 7) * 4 + (bx >> 6)) * 128; n0 = ((bx >> 3) & 7) * 128; }

    f32x4 acc[4][4];
    if (y == 2) gemm_core(Whi, Wlo, xhi, xlo, m0, n0, sA, sB, acc);
    else        gemm_core(xhi, xlo, Whi, Wlo, m0, n0, sA, sB, acc);

    const int tid = threadIdx.x, ln = tid & 63, wave = tid >> 6;
    const int wm = wave >> 1, wn = wave & 1;
    const int rl = ln & 15, kh = ln >> 4;

    if (y == 2) {
        // C[m=d-row][n=s-col] -> VT[(b*16+h)*64+hd][s], row stride VTS
#pragma unroll
        for (int fn = 0; fn < 4; ++fn) {
            const int n  = n0 + wn * 64 + fn * 16 + rl;   // 0..4095
            const int bb = n >> 11, s = n & (SEQ - 1);
#pragma unroll
            for (int fm = 0; fm < 4; ++fm)
#pragma unroll
                for (int r = 0; r < 4; ++r) {
                    const int m = m0 + wm * 64 + fm * 16 + kh * 4 + r;  // 0..1023
                    const float o = acc[fm][fn][r] + bvv[m];
                    const int row = (bb * NHEAD + (m >> 6)) * HDIM + (m & 63);
                    VTo[(size_t)row * VTS + s] = f2bf(o);
                }
        }
    } else {
        const float* bias = (y == 0) ? bq : bk;
        u16* Y = (y == 0) ? Qo : Ko;
        const int b = m0 >> 11;
#pragma unroll
        for (int fn = 0; fn < 4; ++fn) {
            const int n = n0 + wn * 64 + fn * 16 + rl;
            const float bb = bias[n];
            const int h = n >> 6, hd = n & 63;
#pragma unroll
            for (int fm = 0; fm < 4; ++fm)
#pragma unroll
                for (int r = 0; r < 4; ++r) {
                    const int m = m0 + wm * 64 + fm * 16 + kh * 4 + r;
                    const int s = m & (SEQ - 1);
                    Y[((size_t)(b * NHEAD + h) * SEQ + s) * HDIM + hd] =
                        f2bf(acc[fm][fn][r] + bb);
                }
        }
    }
}

// Final projection: out = AO@Wo^T + bo, fp32 out.
__global__ __launch_bounds__(256) void gemm_out(
    const u16* __restrict__ Ahi, const u16* __restrict__ Alo,
    const u16* __restrict__ Bhi, const u16* __restrict__ Blo,
    const float* __restrict__ bias, float* __restrict__ Y)
{
    __shared__ u16 sA[3][4096], sB[3][4096];
    const int bx = blockIdx.x;
    const int mt = (bx & 7) * 4 + (bx >> 6);
    const int nt = (bx >> 3) & 7;
    const int m0 = mt * 128, n0 = nt * 128;

    f32x4 acc[4][4];
    gemm_core(Ahi, Alo, Bhi, Blo, m0, n0, sA, sB, acc);

    const int tid = threadIdx.x, ln = tid & 63, wave = tid >> 6;
    const int wm = wave >> 1, wn = wave & 1;
    const int rl = ln & 15, kh = ln >> 4;
#pragma unroll
    for (int fn = 0; fn < 4; ++fn) {
        const int n = n0 + wn * 64 + fn * 16 + rl;
        const float bb = bias[n];
#pragma unroll
        for (int fm = 0; fm < 4; ++fm)
#pragma unroll
            for (int r = 0; r < 4; ++r) {
                const int m = m0 + wm * 64 + fm * 16 + kh * 4 + r;
                Y[(size_t)m * DMODEL + n] = acc[fm][fn][r] + bb;
            }
    }
}

// ---------------------------------------------------------------------------
// MFMA banded attention (unchanged from round 4 — verified).
// ---------------------------------------------------------------------------
__global__ __launch_bounds__(256) void attn_mfma(
    const u16* __restrict__ Q, const u16* __restrict__ K,
    const u16* __restrict__ VT,
    u16* __restrict__ aohi, u16* __restrict__ aolo)
{
    __shared__ u16 P_lds[4][16][232];   // 232-elem stride: 2-way banks (free)

    const int tid = threadIdx.x, ln = tid & 63, wv = tid >> 6;
    const int bx0 = blockIdx.x;
    const int asg = (bx0 & 7) * 128 + (bx0 >> 3);   // 1024 = 8 XCD * 128
    const int bh  = asg >> 5;
    const int qt  = asg & 31;
    const int b   = bh >> 4, h = bh & 15;
    const int q0  = qt * 64 + wv * 16;
    const int jmin = (q0 >= 104) ? (q0 - 104) : 0;   // == 0 (mod 8)

    const u16* Qbh  = Q  + (size_t)bh * SEQ * HDIM;
    const u16* Kbh  = K  + (size_t)bh * SEQ * HDIM;
    const u16* VTbh = VT + (size_t)bh * HDIM * VTS;

    const int lr = ln & 15, lk = ln >> 4;

    const bf16x8 qf0 = *(const bf16x8*)(Qbh + (size_t)(q0 + lr) * HDIM + lk * 8);
    const bf16x8 qf1 = *(const bf16x8*)(Qbh + (size_t)(q0 + lr) * HDIM + 32 + lk * 8);

    // ---- QK^T: 14 tiles x 2 MFMA ----
    f32x4 sc[14];
#pragma unroll
    for (int t = 0; t < 14; ++t) {
        const int j  = jmin + t * 16 + lr;
        const int jc = min(j, SEQ - 1);          // clamped load; masked below
        const u16* kp = Kbh + (size_t)jc * HDIM + lk * 8;
        const bf16x8 k0 = *(const bf16x8*)kp;
        const bf16x8 k1 = *(const bf16x8*)(kp + 32);
        f32x4 a = (f32x4){0.f, 0.f, 0.f, 0.f};
        a = __builtin_amdgcn_mfma_f32_16x16x32_bf16(qf0, k0, a, 0, 0, 0);
        a = __builtin_amdgcn_mfma_f32_16x16x32_bf16(qf1, k1, a, 0, 0, 0);
        sc[t] = a;
    }

    // ---- masked softmax, per C-row r (16-lane group shares a row) ----
    float lrow[4];
#pragma unroll
    for (int r = 0; r < 4; ++r) {
        const int i = q0 + lk * 4 + r;
        float mx = -3.0e38f;
#pragma unroll
        for (int t = 0; t < 14; ++t) {
            const int j = jmin + t * 16 + lr;
            float v = sc[t][r] * 0.125f;
            const bool ok = (j >= i - HALFW) && (j <= i + HALFW) && (j < SEQ);
            v = ok ? v : -3.0e38f;
            sc[t][r] = v;
            mx = fmaxf(mx, v);
        }
#pragma unroll
        for (int off = 8; off > 0; off >>= 1) mx = fmaxf(mx, __shfl_xor(mx, off));
        float sum = 0.f;
#pragma unroll
        for (int t = 0; t < 14; ++t) {
            const float p = __expf(sc[t][r] - mx);   // masked -> exactly 0
            sum += p;
            P_lds[wv][lk * 4 + r][t * 16 + lr] = f2bf(p);
        }
#pragma unroll
        for (int off = 8; off > 0; off >>= 1) sum += __shfl_xor(sum, off);
        lrow[r] = sum;
    }
    // same-wave LDS write->read; compiler inserts lgkmcnt waits

    // ---- PV: 7 k-chunks x 4 d-tiles, aligned unclamped V^T loads ----
    f32x4 ao[4];
#pragma unroll
    for (int nt = 0; nt < 4; ++nt) ao[nt] = (f32x4){0.f, 0.f, 0.f, 0.f};
#pragma unroll
    for (int kc = 0; kc < 7; ++kc) {
        const bf16x8 pf = *(const bf16x8*)&P_lds[wv][lr][kc * 32 + lk * 8];
        const int jb = jmin + kc * 32 + lk * 8;   // 16B aligned, < VTS
#pragma unroll
        for (int nt = 0; nt < 4; ++nt) {
            const bf16x8 vf = *(const bf16x8*)(VTbh + (size_t)(nt * 16 + lr) * VTS + jb);
            ao[nt] = __builtin_amdgcn_mfma_f32_16x16x32_bf16(pf, vf, ao[nt], 0, 0, 0);
        }
    }

    // ---- epilogue: AO -> hi/lo bf16 [4096][1024] ----
#pragma unroll
    for (int nt = 0; nt < 4; ++nt)
#pragma unroll
        for (int r = 0; r < 4; ++r) {
            const int i = q0 + lk * 4 + r;
            const float o = ao[nt][r] / lrow[r];
            const size_t idx = ((size_t)b * SEQ + i) * DMODEL + h * HDIM + nt * 16 + lr;
            const u16 hh = f2bf(o);
            aohi[idx] = hh;
            aolo[idx] = f2bf(o - bf2f(hh));
        }
}

// ---------------------------------------------------------------------------
// Round-1 fp32 path (fallback only).
// ---------------------------------------------------------------------------
template<int QKV>
__global__ __launch_bounds__(256) void gemm_xwt(
    const float* __restrict__ X, const float* __restrict__ W,
    const float* __restrict__ bias, float* __restrict__ Y)
{
    __shared__ float As[16][132];
    __shared__ float Bs[16][68];
    const int tid = threadIdx.x;
    const int bx  = blockIdx.x;
    const int n0  = (bx & 15) * 64;
    const int m0  = (bx >> 4) * 128;
    const int ty  = tid >> 4, tx = tid & 15;
    float acc[8][4];
#pragma unroll
    for (int r = 0; r < 8; ++r)
#pragma unroll
        for (int c = 0; c < 4; ++c) acc[r][c] = 0.f;
    const int lrow = tid >> 2, lkq = (tid & 3) * 4;
    for (int k0 = 0; k0 < DMODEL; k0 += 16) {
        float4 a0 = *(const float4*)(X + (size_t)(m0 + lrow)      * DMODEL + k0 + lkq);
        float4 a1 = *(const float4*)(X + (size_t)(m0 + lrow + 64) * DMODEL + k0 + lkq);
        float4 b0 = *(const float4*)(W + (size_t)(n0 + lrow)      * DMODEL + k0 + lkq);
        __syncthreads();
        As[lkq + 0][lrow] = a0.x; As[lkq + 1][lrow] = a0.y;
        As[lkq + 2][lrow] = a0.z; As[lkq + 3][lrow] = a0.w;
        As[lkq + 0][lrow + 64] = a1.x; As[lkq + 1][lrow + 64] = a1.y;
        As[lkq + 2][lrow + 64] = a1.z; As[lkq + 3][lrow + 64] = a1.w;
        Bs[lkq + 0][lrow] = b0.x; Bs[lkq + 1][lrow] = b0.y;
        Bs[lkq + 2][lrow] = b0.z; Bs[lkq + 3][lrow] = b0.w;
        __syncthreads();
#pragma unroll
        for (int k = 0; k < 16; ++k) {
            float4 av0 = *(const float4*)&As[k][ty * 8];
            float4 av1 = *(const float4*)&As[k][ty * 8 + 4];
            float4 bv  = *(const float4*)&Bs[k][tx * 4];
            float a[8] = {av0.x, av0.y, av0.z, av0.w, av1.x, av1.y, av1.z, av1.w};
            float bb[4] = {bv.x, bv.y, bv.z, bv.w};
#pragma unroll
            for (int r = 0; r < 8; ++r)
#pragma unroll
                for (int c = 0; c < 4; ++c) acc[r][c] += a[r] * bb[c];
        }
    }
    const float4 bb = *(const float4*)(bias + n0 + tx * 4);
    if (QKV) {
        const int b = m0 >> 11, h = n0 >> 6;
#pragma unroll
        for (int r = 0; r < 8; ++r) {
            const int m = m0 + ty * 8 + r, ss = m & (SEQ - 1);
            float4 o = {acc[r][0] + bb.x, acc[r][1] + bb.y, acc[r][2] + bb.z, acc[r][3] + bb.w};
            *(float4*)(Y + ((size_t)(b * NHEAD + h) * SEQ + ss) * HDIM + tx * 4) = o;
        }
    } else {
#pragma unroll
        for (int r = 0; r < 8; ++r) {
            const int m = m0 + ty * 8 + r;
            float4 o = {acc[r][0] + bb.x, acc[r][1] + bb.y, acc[r][2] + bb.z, acc[r][3] + bb.w};
            *(float4*)(Y + (size_t)m * DMODEL + n0 + tx * 4) = o;
        }
    }
}

__global__ __launch_bounds__(256) void attn_local_f32(
    const float* __restrict__ Q, const float* __restrict__ K,
    const float* __restrict__ V, float* __restrict__ O)
{
    __shared__ float ssc[32][BWMAX];
    const int tid = threadIdx.x;
    const int bx0 = blockIdx.x;
    const int bx  = (bx0 & 7) * 256 + (bx0 >> 3);
    const int qt  = bx & 63;
    const int h   = (bx >> 6) & 15;
    const int b   = bx >> 10;
    const int i0  = qt * 32;
    const int jmin = max(0, i0 - HALFW);
    const int jmax = min(SEQ - 1, i0 + 31 + HALFW);
    const int BWt  = jmax - jmin + 1;
    const float* Qbh = Q + (size_t)(b * NHEAD + h) * SEQ * HDIM;
    const float* Kbh = K + (size_t)(b * NHEAD + h) * SEQ * HDIM;
    const float* Vbh = V + (size_t)(b * NHEAD + h) * SEQ * HDIM;
    const int jj = tid;
    if (jj < BWt) {
        float acc[32];
#pragma unroll
        for (int i = 0; i < 32; ++i) acc[i] = 0.f;
        const float* kp = Kbh + (size_t)(jmin + jj) * HDIM;
        for (int d0 = 0; d0 < HDIM; d0 += 4) {
            const float4 kv = *(const float4*)(kp + d0);
#pragma unroll
            for (int i = 0; i < 32; ++i) {
                const float4 qv = *(const float4*)(Qbh + (size_t)(i0 + i) * HDIM + d0);
                acc[i] += qv.x * kv.x + qv.y * kv.y + qv.z * kv.z + qv.w * kv.w;
            }
        }
#pragma unroll
        for (int i = 0; i < 32; ++i) ssc[i][jj] = acc[i] * 0.125f;
    }
    __syncthreads();
    const int wv = tid >> 6, ln = tid & 63;
    float rs[8];
#pragma unroll
    for (int r = 0; r < 8; ++r) {
        const int i  = wv * 8 + r;
        const int qi = i0 + i;
        const int lo = max(0, qi - HALFW) - jmin;
        const int hi = min(SEQ - 1, qi + HALFW) - jmin;
        float m = -1e30f;
#pragma unroll
        for (int c = 0; c < 4; ++c) {
            const int j = ln + 64 * c;
            if (j >= lo && j <= hi) m = fmaxf(m, ssc[i][j]);
        }
#pragma unroll
        for (int off = 32; off > 0; off >>= 1) m = fmaxf(m, __shfl_xor(m, off));
        float sum = 0.f;
#pragma unroll
        for (int c = 0; c < 4; ++c) {
            const int j = ln + 64 * c;
            if (j < BWt) {
                float p = 0.f;
                if (j >= lo && j <= hi) p = __expf(ssc[i][j] - m);
                ssc[i][j] = p;
                sum += p;
            }
        }
#pragma unroll
        for (int off = 32; off > 0; off >>= 1) sum += __shfl_xor(sum, off);
        rs[r] = sum;
    }
    float oa[8];
#pragma unroll
    for (int r = 0; r < 8; ++r) oa[r] = 0.f;
    int jq = 0;
    for (; jq + 4 <= BWt; jq += 4) {
        const float v0 = Vbh[(size_t)(jmin + jq + 0) * HDIM + ln];
        const float v1 = Vbh[(size_t)(jmin + jq + 1) * HDIM + ln];
        const float v2 = Vbh[(size_t)(jmin + jq + 2) * HDIM + ln];
        const float v3 = Vbh[(size_t)(jmin + jq + 3) * HDIM + ln];
#pragma unroll
        for (int r = 0; r < 8; ++r) {
            const float4 p4 = *(const float4*)&ssc[wv * 8 + r][jq];
            oa[r] += p4.x * v0 + p4.y * v1 + p4.z * v2 + p4.w * v3;
        }
    }
    for (; jq < BWt; ++jq) {
        const float v0 = Vbh[(size_t)(jmin + jq) * HDIM + ln];
#pragma unroll
        for (int r = 0; r < 8; ++r) oa[r] += ssc[wv * 8 + r][jq] * v0;
    }
#pragma unroll
    for (int r = 0; r < 8; ++r) {
        const int i = i0 + wv * 8 + r;
        O[((size_t)b * SEQ + i) * DMODEL + h * HDIM + ln] = oa[r] / rs[r];
    }
}

// ---------------------------------------------------------------------------
extern "C" void kernel_launch(void* const* d_in, const int* in_sizes, int n_in,
                              void* d_out, int out_size, void* d_ws, size_t ws_size,
                              hipStream_t stream) {
    const float* x  = (const float*)d_in[0];
    const float* Wq = (const float*)d_in[1];
    const float* bq = (const float*)d_in[2];
    const float* Wk = (const float*)d_in[3];
    const float* bk = (const float*)d_in[4];
    const float* Wv = (const float*)d_in[5];
    const float* bv = (const float*)d_in[6];
    const float* Wo = (const float*)d_in[7];
    const float* bo = (const float*)d_in[8];

    float* out = (float*)d_out;

    const size_t REQUIRED = (size_t)80 * 1024 * 1024;
    if (ws_size >= REQUIRED) {
        const size_t M4 = 4194304;                       // 4M u16 = 8MB
        const size_t VT_ELEMS = (size_t)32 * HDIM * VTS; // 4,456,448 u16
        u16* Qb    = (u16*)d_ws;
        u16* Kb    = Qb + M4;
        u16* VTb   = Kb + M4;
        u16* aohi  = VTb + VT_ELEMS;
        u16* aolo  = aohi + M4;
        u16* xhi   = aolo + M4;
        u16* xlo   = xhi + M4;
        u16* wbase = xlo + M4;                           // 8M u16 = 16MB (total ~73MB)

        hipMemsetAsync(VTb, 0, VT_ELEMS * sizeof(u16), stream);  // zero pad cols
        split5<<<dim3(4096, 5), 256, 0, stream>>>(x, Wq, Wk, Wv, Wo, xhi, xlo, wbase);
        gemm_qkv<<<dim3(256, 3), 256, 0, stream>>>(xhi, xlo, wbase, bq, bk, bv, Qb, Kb, VTb);
        attn_mfma<<<1024, 256, 0, stream>>>(Qb, Kb, VTb, aohi, aolo);
        gemm_out<<<256, 256, 0, stream>>>(aohi, aolo, wbase + 6291456, wbase + 7340032, bo, out);
    } else {
        float* ws = (float*)d_ws;
        const size_t NELEM = (size_t)2 * SEQ * DMODEL;
        float* Qb = ws;
        float* Kb = ws + NELEM;
        float* Vb = ws + 2 * NELEM;
        float* AO = ws + 3 * NELEM;
        gemm_xwt<1><<<512, 256, 0, stream>>>(x, Wq, bq, Qb);
        gemm_xwt<1><<<512, 256, 0, stream>>>(x, Wk, bk, Kb);
        gemm_xwt<1><<<512, 256, 0, stream>>>(x, Wv, bv, Vb);
        attn_local_f32<<<2048, 256, 0, stream>>>(Qb, Kb, Vb, AO);
        gemm_xwt<0><<<512, 256, 0, stream>>>(AO, Wo, bo, out);
    }
}

// Round 6
// 221.101 us; speedup vs baseline: 1.2198x; 1.2198x over previous
//
#include <hip/hip_runtime.h>

// FixedSparseMultiHead: B=2, S=2048, D=1024, H=16, Hd=64, local band ±102.
// Round 6: K-major fused 3-product gemm_core.
//   - One pass over K (32 steps, BK=32): stage Ahi/Alo/Bhi/Blo once per step,
//     48 MFMA per barrier (was 16) -> 3x fewer sync drains, -33% staging traffic.
//   - Round-4-style __syncthreads double-buffer (compiler-managed vmcnt drains;
//     verified race-free); round-5 conflict-free LDS chunk layout retained.
//   - LDS 64KB -> 2 blocks/CU.
// Pipeline: split5 -> gemm_qkv (Q,K bf16 [B,H,S,64]; V^T bf16 [B,H,64,2176])
//           -> attn_mfma -> gemm_out. Fallback fp32 path if ws_size < 80MB.

#define SEQ    2048
#define DMODEL 1024
#define NHEAD  16
#define HDIM   64
#define HALFW  102
#define BWMAX  240
#define VTS    2176    // padded V^T row stride (zeros beyond SEQ)

typedef unsigned short u16;
typedef __attribute__((ext_vector_type(8))) short bf16x8;
typedef __attribute__((ext_vector_type(4))) float f32x4;

__device__ __forceinline__ u16 f2bf(float f) {
    unsigned u = __builtin_bit_cast(unsigned, f);
    unsigned r = (u + 0x7fffu + ((u >> 16) & 1u)) >> 16;   // RNE
    return (u16)r;
}
__device__ __forceinline__ float bf2f(u16 u) {
    return __builtin_bit_cast(float, ((unsigned)u) << 16);
}

__device__ __forceinline__ void gload16(const void* g, void* l) {
    __builtin_amdgcn_global_load_lds(
        (const __attribute__((address_space(1))) void*)g,
        (__attribute__((address_space(3))) void*)l, 16, 0, 0);
}

// ---------------------------------------------------------------------------
// split: fp32 -> (hi,lo) bf16.  y=0: x (4M elems); y=1..4: Wq/Wk/Wv/Wo (1M).
// ---------------------------------------------------------------------------
__global__ __launch_bounds__(256) void split5(
    const float* __restrict__ x,  const float* __restrict__ wq,
    const float* __restrict__ wk, const float* __restrict__ wv,
    const float* __restrict__ wo,
    u16* __restrict__ xhi, u16* __restrict__ xlo, u16* __restrict__ wbase)
{
    const int y = blockIdx.y;
    const float* src; u16* hi; u16* lo; int nblk;
    switch (y) {
      case 0:  src = x;  hi = xhi;             lo = xlo;             nblk = 4096; break;
      case 1:  src = wq; hi = wbase;           lo = wbase + 1048576; nblk = 1024; break;
      case 2:  src = wk; hi = wbase + 2097152; lo = wbase + 3145728; nblk = 1024; break;
      case 3:  src = wv; hi = wbase + 4194304; lo = wbase + 5242880; nblk = 1024; break;
      default: src = wo; hi = wbase + 6291456; lo = wbase + 7340032; nblk = 1024; break;
    }
    const int bx = blockIdx.x;
    if (bx >= nblk) return;
    const int i = (bx * 256 + threadIdx.x) * 4;
    const float4 v = *(const float4*)(src + i);
    ushort4 h, l;
    h.x = f2bf(v.x); l.x = f2bf(v.x - bf2f(h.x));
    h.y = f2bf(v.y); l.y = f2bf(v.y - bf2f(h.y));
    h.z = f2bf(v.z); l.z = f2bf(v.z - bf2f(h.z));
    h.w = f2bf(v.w); l.w = f2bf(v.w - bf2f(h.w));
    *(ushort4*)(hi + i) = h;
    *(ushort4*)(lo + i) = l;
}

// ---------------------------------------------------------------------------
// MFMA GEMM core, K-major: C[128x128] = Ahi*Bhi^T + Alo*Bhi^T + Ahi*Blo^T,
// K=1024, BK=32, 32 steps. 256 thr = 4 waves (2x2 of 64x64).
// LDS: per operand-variant 2 buffers of 8 chunks x [4 khalf][16 row][8 elem]
//   (chunk = 1KB, lane-linear: gload_lds dst = chunk + ln*16B; fragment
//   ds_read_b128 at chunk + ln*16B -> conflict-free; verified r5).
// Schedule (round-4 template): stage(buf0); sync;
//   loop t: { stage(buf^1, t+1); read 16 frags; 48 MFMA; sync; }
// __syncthreads' vmcnt(0)+lgkmcnt(0) drain makes overwrite race-free.
// ---------------------------------------------------------------------------
__device__ __forceinline__ void gemm_core(
    const u16* __restrict__ Ahi, const u16* __restrict__ Alo,
    const u16* __restrict__ Bhi, const u16* __restrict__ Blo,
    int m0, int n0,
    u16 (*sAh)[4096], u16 (*sAl)[4096], u16 (*sBh)[4096], u16 (*sBl)[4096],
    f32x4 acc[4][4])
{
    const int tid = threadIdx.x, ln = tid & 63, wave = tid >> 6;
    const int wm = wave >> 1, wn = wave & 1;
    const int srow = ln & 15, scol = (ln >> 4) * 8;

#pragma unroll
    for (int fm = 0; fm < 4; ++fm)
#pragma unroll
        for (int fn = 0; fn < 4; ++fn) acc[fm][fn] = (f32x4){0.f, 0.f, 0.f, 0.f};

    auto stage = [&](int buf, int k0) {
#pragma unroll
        for (int c = wave; c < 8; c += 4) {        // 2 chunks per wave per tile
            const size_t ar = (size_t)(m0 + c * 16 + srow) * 1024 + k0 + scol;
            const size_t br = (size_t)(n0 + c * 16 + srow) * 1024 + k0 + scol;
            gload16(Ahi + ar, sAh[buf] + c * 512);
            gload16(Alo + ar, sAl[buf] + c * 512);
            gload16(Bhi + br, sBh[buf] + c * 512);
            gload16(Blo + br, sBl[buf] + c * 512);
        }
    };

    stage(0, 0);
    __syncthreads();

    for (int t = 0; t < 32; ++t) {
        const int cur = t & 1;
        if (t + 1 < 32) stage(cur ^ 1, (t + 1) << 5);

        bf16x8 ah[4], al[4], bh[4], bl[4];
#pragma unroll
        for (int f = 0; f < 4; ++f) {
            const int ca = (wm * 4 + f) * 512 + ln * 8;
            const int cb = (wn * 4 + f) * 512 + ln * 8;
            ah[f] = *(const bf16x8*)(sAh[cur] + ca);
            al[f] = *(const bf16x8*)(sAl[cur] + ca);
            bh[f] = *(const bf16x8*)(sBh[cur] + cb);
            bl[f] = *(const bf16x8*)(sBl[cur] + cb);
        }
#pragma unroll
        for (int fm = 0; fm < 4; ++fm)
#pragma unroll
            for (int fn = 0; fn < 4; ++fn) {
                f32x4 c = acc[fm][fn];
                c = __builtin_amdgcn_mfma_f32_16x16x32_bf16(ah[fm], bh[fn], c, 0, 0, 0);
                c = __builtin_amdgcn_mfma_f32_16x16x32_bf16(al[fm], bh[fn], c, 0, 0, 0);
                c = __builtin_amdgcn_mfma_f32_16x16x32_bf16(ah[fm], bl[fn], c, 0, 0, 0);
                acc[fm][fn] = c;
            }
        __syncthreads();
    }
}

// ---------------------------------------------------------------------------
// Fused Q/K/V^T projection. y=0: Q bf16 [B,H,S,64]; y=1: K bf16 [B,H,S,64];
// y=2: V^T bf16 [B,H,64,VTS] via swapped operands (A=Wv, B=x).
// ---------------------------------------------------------------------------
__global__ __launch_bounds__(256) void gemm_qkv(
    const u16* __restrict__ xhi, const u16* __restrict__ xlo,
    const u16* __restrict__ wbase,
    const float* __restrict__ bq, const float* __restrict__ bk,
    const float* __restrict__ bvv,
    u16* __restrict__ Qo, u16* __restrict__ Ko, u16* __restrict__ VTo)
{
    __shared__ u16 sAh[2][4096], sAl[2][4096], sBh[2][4096], sBl[2][4096]; // 64KB
    const int y = blockIdx.y;
    const u16* Whi = wbase + (size_t)y * 2097152;
    const u16* Wlo = Whi + 1048576;

    const int bx = blockIdx.x;
    int m0, n0;
    if (y == 2) { m0 = (bx & 7) * 128; n0 = (bx >> 3) * 128; }          // m over D, n over 4096
    else { m0 = ((bx & 7) * 4 + (bx >> 6)) * 128; n0 = ((bx >> 3) & 7) * 128; }

    f32x4 acc[4][4];
    if (y == 2) gemm_core(Whi, Wlo, xhi, xlo, m0, n0, sAh, sAl, sBh, sBl, acc);
    else        gemm_core(xhi, xlo, Whi, Wlo, m0, n0, sAh, sAl, sBh, sBl, acc);

    const int tid = threadIdx.x, ln = tid & 63, wave = tid >> 6;
    const int wm = wave >> 1, wn = wave & 1;
    const int rl = ln & 15, kh = ln >> 4;

    if (y == 2) {
        // C[m=d-row][n=s-col] -> VT[(b*16+h)*64+hd][s], row stride VTS
#pragma unroll
        for (int fn = 0; fn < 4; ++fn) {
            const int n  = n0 + wn * 64 + fn * 16 + rl;   // 0..4095
            const int bb = n >> 11, s = n & (SEQ - 1);
#pragma unroll
            for (int fm = 0; fm < 4; ++fm)
#pragma unroll
                for (int r = 0; r < 4; ++r) {
                    const int m = m0 + wm * 64 + fm * 16 + kh * 4 + r;  // 0..1023
                    const float o = acc[fm][fn][r] + bvv[m];
                    const int row = (bb * NHEAD + (m >> 6)) * HDIM + (m & 63);
                    VTo[(size_t)row * VTS + s] = f2bf(o);
                }
        }
    } else {
        const float* bias = (y == 0) ? bq : bk;
        u16* Y = (y == 0) ? Qo : Ko;
        const int b = m0 >> 11;
#pragma unroll
        for (int fn = 0; fn < 4; ++fn) {
            const int n = n0 + wn * 64 + fn * 16 + rl;
            const float bb = bias[n];
            const int h = n >> 6, hd = n & 63;
#pragma unroll
            for (int fm = 0; fm < 4; ++fm)
#pragma unroll
                for (int r = 0; r < 4; ++r) {
                    const int m = m0 + wm * 64 + fm * 16 + kh * 4 + r;
                    const int s = m & (SEQ - 1);
                    Y[((size_t)(b * NHEAD + h) * SEQ + s) * HDIM + hd] =
                        f2bf(acc[fm][fn][r] + bb);
                }
        }
    }
}

// Final projection: out = AO@Wo^T + bo, fp32 out.
__global__ __launch_bounds__(256) void gemm_out(
    const u16* __restrict__ Ahi, const u16* __restrict__ Alo,
    const u16* __restrict__ Bhi, const u16* __restrict__ Blo,
    const float* __restrict__ bias, float* __restrict__ Y)
{
    __shared__ u16 sAh[2][4096], sAl[2][4096], sBh[2][4096], sBl[2][4096]; // 64KB
    const int bx = blockIdx.x;
    const int mt = (bx & 7) * 4 + (bx >> 6);
    const int nt = (bx >> 3) & 7;
    const int m0 = mt * 128, n0 = nt * 128;

    f32x4 acc[4][4];
    gemm_core(Ahi, Alo, Bhi, Blo, m0, n0, sAh, sAl, sBh, sBl, acc);

    const int tid = threadIdx.x, ln = tid & 63, wave = tid >> 6;
    const int wm = wave >> 1, wn = wave & 1;
    const int rl = ln & 15, kh = ln >> 4;
#pragma unroll
    for (int fn = 0; fn < 4; ++fn) {
        const int n = n0 + wn * 64 + fn * 16 + rl;
        const float bb = bias[n];
#pragma unroll
        for (int fm = 0; fm < 4; ++fm)
#pragma unroll
            for (int r = 0; r < 4; ++r) {
                const int m = m0 + wm * 64 + fm * 16 + kh * 4 + r;
                Y[(size_t)m * DMODEL + n] = acc[fm][fn][r] + bb;
            }
    }
}

// ---------------------------------------------------------------------------
// MFMA banded attention (unchanged from round 4 — verified).
// ---------------------------------------------------------------------------
__global__ __launch_bounds__(256) void attn_mfma(
    const u16* __restrict__ Q, const u16* __restrict__ K,
    const u16* __restrict__ VT,
    u16* __restrict__ aohi, u16* __restrict__ aolo)
{
    __shared__ u16 P_lds[4][16][232];   // 232-elem stride: 2-way banks (free)

    const int tid = threadIdx.x, ln = tid & 63, wv = tid >> 6;
    const int bx0 = blockIdx.x;
    const int asg = (bx0 & 7) * 128 + (bx0 >> 3);   // 1024 = 8 XCD * 128
    const int bh  = asg >> 5;
    const int qt  = asg & 31;
    const int b   = bh >> 4, h = bh & 15;
    const int q0  = qt * 64 + wv * 16;
    const int jmin = (q0 >= 104) ? (q0 - 104) : 0;   // == 0 (mod 8)

    const u16* Qbh  = Q  + (size_t)bh * SEQ * HDIM;
    const u16* Kbh  = K  + (size_t)bh * SEQ * HDIM;
    const u16* VTbh = VT + (size_t)bh * HDIM * VTS;

    const int lr = ln & 15, lk = ln >> 4;

    const bf16x8 qf0 = *(const bf16x8*)(Qbh + (size_t)(q0 + lr) * HDIM + lk * 8);
    const bf16x8 qf1 = *(const bf16x8*)(Qbh + (size_t)(q0 + lr) * HDIM + 32 + lk * 8);

    // ---- QK^T: 14 tiles x 2 MFMA ----
    f32x4 sc[14];
#pragma unroll
    for (int t = 0; t < 14; ++t) {
        const int j  = jmin + t * 16 + lr;
        const int jc = min(j, SEQ - 1);          // clamped load; masked below
        const u16* kp = Kbh + (size_t)jc * HDIM + lk * 8;
        const bf16x8 k0 = *(const bf16x8*)kp;
        const bf16x8 k1 = *(const bf16x8*)(kp + 32);
        f32x4 a = (f32x4){0.f, 0.f, 0.f, 0.f};
        a = __builtin_amdgcn_mfma_f32_16x16x32_bf16(qf0, k0, a, 0, 0, 0);
        a = __builtin_amdgcn_mfma_f32_16x16x32_bf16(qf1, k1, a, 0, 0, 0);
        sc[t] = a;
    }

    // ---- masked softmax, per C-row r (16-lane group shares a row) ----
    float lrow[4];
#pragma unroll
    for (int r = 0; r < 4; ++r) {
        const int i = q0 + lk * 4 + r;
        float mx = -3.0e38f;
#pragma unroll
        for (int t = 0; t < 14; ++t) {
            const int j = jmin + t * 16 + lr;
            float v = sc[t][r] * 0.125f;
            const bool ok = (j >= i - HALFW) && (j <= i + HALFW) && (j < SEQ);
            v = ok ? v : -3.0e38f;
            sc[t][r] = v;
            mx = fmaxf(mx, v);
        }
#pragma unroll
        for (int off = 8; off > 0; off >>= 1) mx = fmaxf(mx, __shfl_xor(mx, off));
        float sum = 0.f;
#pragma unroll
        for (int t = 0; t < 14; ++t) {
            const float p = __expf(sc[t][r] - mx);   // masked -> exactly 0
            sum += p;
            P_lds[wv][lk * 4 + r][t * 16 + lr] = f2bf(p);
        }
#pragma unroll
        for (int off = 8; off > 0; off >>= 1) sum += __shfl_xor(sum, off);
        lrow[r] = sum;
    }
    // same-wave LDS write->read; compiler inserts lgkmcnt waits

    // ---- PV: 7 k-chunks x 4 d-tiles, aligned unclamped V^T loads ----
    f32x4 ao[4];
#pragma unroll
    for (int nt = 0; nt < 4; ++nt) ao[nt] = (f32x4){0.f, 0.f, 0.f, 0.f};
#pragma unroll
    for (int kc = 0; kc < 7; ++kc) {
        const bf16x8 pf = *(const bf16x8*)&P_lds[wv][lr][kc * 32 + lk * 8];
        const int jb = jmin + kc * 32 + lk * 8;   // 16B aligned, < VTS
#pragma unroll
        for (int nt = 0; nt < 4; ++nt) {
            const bf16x8 vf = *(const bf16x8*)(VTbh + (size_t)(nt * 16 + lr) * VTS + jb);
            ao[nt] = __builtin_amdgcn_mfma_f32_16x16x32_bf16(pf, vf, ao[nt], 0, 0, 0);
        }
    }

    // ---- epilogue: AO -> hi/lo bf16 [4096][1024] ----
#pragma unroll
    for (int nt = 0; nt < 4; ++nt)
#pragma unroll
        for (int r = 0; r < 4; ++r) {
            const int i = q0 + lk * 4 + r;
            const float o = ao[nt][r] / lrow[r];
            const size_t idx = ((size_t)b * SEQ + i) * DMODEL + h * HDIM + nt * 16 + lr;
            const u16 hh = f2bf(o);
            aohi[idx] = hh;
            aolo[idx] = f2bf(o - bf2f(hh));
        }
}

// ---------------------------------------------------------------------------
// Round-1 fp32 path (fallback only).
// ---------------------------------------------------------------------------
template<int QKV>
__global__ __launch_bounds__(256) void gemm_xwt(
    const float* __restrict__ X, const float* __restrict__ W,
    const float* __restrict__ bias, float* __restrict__ Y)
{
    __shared__ float As[16][132];
    __shared__ float Bs[16][68];
    const int tid = threadIdx.x;
    const int bx  = blockIdx.x;
    const int n0  = (bx & 15) * 64;
    const int m0  = (bx >> 4) * 128;
    const int ty  = tid >> 4, tx = tid & 15;
    float acc[8][4];
#pragma unroll
    for (int r = 0; r < 8; ++r)
#pragma unroll
        for (int c = 0; c < 4; ++c) acc[r][c] = 0.f;
    const int lrow = tid >> 2, lkq = (tid & 3) * 4;
    for (int k0 = 0; k0 < DMODEL; k0 += 16) {
        float4 a0 = *(const float4*)(X + (size_t)(m0 + lrow)      * DMODEL + k0 + lkq);
        float4 a1 = *(const float4*)(X + (size_t)(m0 + lrow + 64) * DMODEL + k0 + lkq);
        float4 b0 = *(const float4*)(W + (size_t)(n0 + lrow)      * DMODEL + k0 + lkq);
        __syncthreads();
        As[lkq + 0][lrow] = a0.x; As[lkq + 1][lrow] = a0.y;
        As[lkq + 2][lrow] = a0.z; As[lkq + 3][lrow] = a0.w;
        As[lkq + 0][lrow + 64] = a1.x; As[lkq + 1][lrow + 64] = a1.y;
        As[lkq + 2][lrow + 64] = a1.z; As[lkq + 3][lrow + 64] = a1.w;
        Bs[lkq + 0][lrow] = b0.x; Bs[lkq + 1][lrow] = b0.y;
        Bs[lkq + 2][lrow] = b0.z; Bs[lkq + 3][lrow] = b0.w;
        __syncthreads();
#pragma unroll
        for (int k = 0; k < 16; ++k) {
            float4 av0 = *(const float4*)&As[k][ty * 8];
            float4 av1 = *(const float4*)&As[k][ty * 8 + 4];
            float4 bv  = *(const float4*)&Bs[k][tx * 4];
            float a[8] = {av0.x, av0.y, av0.z, av0.w, av1.x, av1.y, av1.z, av1.w};
            float bb[4] = {bv.x, bv.y, bv.z, bv.w};
#pragma unroll
            for (int r = 0; r < 8; ++r)
#pragma unroll
                for (int c = 0; c < 4; ++c) acc[r][c] += a[r] * bb[c];
        }
    }
    const float4 bb = *(const float4*)(bias + n0 + tx * 4);
    if (QKV) {
        const int b = m0 >> 11, h = n0 >> 6;
#pragma unroll
        for (int r = 0; r < 8; ++r) {
            const int m = m0 + ty * 8 + r, ss = m & (SEQ - 1);
            float4 o = {acc[r][0] + bb.x, acc[r][1] + bb.y, acc[r][2] + bb.z, acc[r][3] + bb.w};
            *(float4*)(Y + ((size_t)(b * NHEAD + h) * SEQ + ss) * HDIM + tx * 4) = o;
        }
    } else {
#pragma unroll
        for (int r = 0; r < 8; ++r) {
            const int m = m0 + ty * 8 + r;
            float4 o = {acc[r][0] + bb.x, acc[r][1] + bb.y, acc[r][2] + bb.z, acc[r][3] + bb.w};
            *(float4*)(Y + (size_t)m * DMODEL + n0 + tx * 4) = o;
        }
    }
}

__global__ __launch_bounds__(256) void attn_local_f32(
    const float* __restrict__ Q, const float* __restrict__ K,
    const float* __restrict__ V, float* __restrict__ O)
{
    __shared__ float ssc[32][BWMAX];
    const int tid = threadIdx.x;
    const int bx0 = blockIdx.x;
    const int bx  = (bx0 & 7) * 256 + (bx0 >> 3);
    const int qt  = bx & 63;
    const int h   = (bx >> 6) & 15;
    const int b   = bx >> 10;
    const int i0  = qt * 32;
    const int jmin = max(0, i0 - HALFW);
    const int jmax = min(SEQ - 1, i0 + 31 + HALFW);
    const int BWt  = jmax - jmin + 1;
    const float* Qbh = Q + (size_t)(b * NHEAD + h) * SEQ * HDIM;
    const float* Kbh = K + (size_t)(b * NHEAD + h) * SEQ * HDIM;
    const float* Vbh = V + (size_t)(b * NHEAD + h) * SEQ * HDIM;
    const int jj = tid;
    if (jj < BWt) {
        float acc[32];
#pragma unroll
        for (int i = 0; i < 32; ++i) acc[i] = 0.f;
        const float* kp = Kbh + (size_t)(jmin + jj) * HDIM;
        for (int d0 = 0; d0 < HDIM; d0 += 4) {
            const float4 kv = *(const float4*)(kp + d0);
#pragma unroll
            for (int i = 0; i < 32; ++i) {
                const float4 qv = *(const float4*)(Qbh + (size_t)(i0 + i) * HDIM + d0);
                acc[i] += qv.x * kv.x + qv.y * kv.y + qv.z * kv.z + qv.w * kv.w;
            }
        }
#pragma unroll
        for (int i = 0; i < 32; ++i) ssc[i][jj] = acc[i] * 0.125f;
    }
    __syncthreads();
    const int wv = tid >> 6, ln = tid & 63;
    float rs[8];
#pragma unroll
    for (int r = 0; r < 8; ++r) {
        const int i  = wv * 8 + r;
        const int qi = i0 + i;
        const int lo = max(0, qi - HALFW) - jmin;
        const int hi = min(SEQ - 1, qi + HALFW) - jmin;
        float m = -1e30f;
#pragma unroll
        for (int c = 0; c < 4; ++c) {
            const int j = ln + 64 * c;
            if (j >= lo && j <= hi) m = fmaxf(m, ssc[i][j]);
        }
#pragma unroll
        for (int off = 32; off > 0; off >>= 1) m = fmaxf(m, __shfl_xor(m, off));
        float sum = 0.f;
#pragma unroll
        for (int c = 0; c < 4; ++c) {
            const int j = ln + 64 * c;
            if (j < BWt) {
                float p = 0.f;
                if (j >= lo && j <= hi) p = __expf(ssc[i][j] - m);
                ssc[i][j] = p;
                sum += p;
            }
        }
#pragma unroll
        for (int off = 32; off > 0; off >>= 1) sum += __shfl_xor(sum, off);
        rs[r] = sum;
    }
    float oa[8];
#pragma unroll
    for (int r = 0; r < 8; ++r) oa[r] = 0.f;
    int jq = 0;
    for (; jq + 4 <= BWt; jq += 4) {
        const float v0 = Vbh[(size_t)(jmin + jq + 0) * HDIM + ln];
        const float v1 = Vbh[(size_t)(jmin + jq + 1) * HDIM + ln];
        const float v2 = Vbh[(size_t)(jmin + jq + 2) * HDIM + ln];
        const float v3 = Vbh[(size_t)(jmin + jq + 3) * HDIM + ln];
#pragma unroll
        for (int r = 0; r < 8; ++r) {
            const float4 p4 = *(const float4*)&ssc[wv * 8 + r][jq];
            oa[r] += p4.x * v0 + p4.y * v1 + p4.z * v2 + p4.w * v3;
        }
    }
    for (; jq < BWt; ++jq) {
        const float v0 = Vbh[(size_t)(jmin + jq) * HDIM + ln];
#pragma unroll
        for (int r = 0; r < 8; ++r) oa[r] += ssc[wv * 8 + r][jq] * v0;
    }
#pragma unroll
    for (int r = 0; r < 8; ++r) {
        const int i = i0 + wv * 8 + r;
        O[((size_t)b * SEQ + i) * DMODEL + h * HDIM + ln] = oa[r] / rs[r];
    }
}

// ---------------------------------------------------------------------------
extern "C" void kernel_launch(void* const* d_in, const int* in_sizes, int n_in,
                              void* d_out, int out_size, void* d_ws, size_t ws_size,
                              hipStream_t stream) {
    const float* x  = (const float*)d_in[0];
    const float* Wq = (const float*)d_in[1];
    const float* bq = (const float*)d_in[2];
    const float* Wk = (const float*)d_in[3];
    const float* bk = (const float*)d_in[4];
    const float* Wv = (const float*)d_in[5];
    const float* bv = (const float*)d_in[6];
    const float* Wo = (const float*)d_in[7];
    const float* bo = (const float*)d_in[8];

    float* out = (float*)d_out;

    const size_t REQUIRED = (size_t)80 * 1024 * 1024;
    if (ws_size >= REQUIRED) {
        const size_t M4 = 4194304;                       // 4M u16 = 8MB
        const size_t VT_ELEMS = (size_t)32 * HDIM * VTS; // 4,456,448 u16
        u16* Qb    = (u16*)d_ws;
        u16* Kb    = Qb + M4;
        u16* VTb   = Kb + M4;
        u16* aohi  = VTb + VT_ELEMS;
        u16* aolo  = aohi + M4;
        u16* xhi   = aolo + M4;
        u16* xlo   = xhi + M4;
        u16* wbase = xlo + M4;                           // 8M u16 = 16MB (total ~73MB)

        hipMemsetAsync(VTb, 0, VT_ELEMS * sizeof(u16), stream);  // zero pad cols
        split5<<<dim3(4096, 5), 256, 0, stream>>>(x, Wq, Wk, Wv, Wo, xhi, xlo, wbase);
        gemm_qkv<<<dim3(256, 3), 256, 0, stream>>>(xhi, xlo, wbase, bq, bk, bv, Qb, Kb, VTb);
        attn_mfma<<<1024, 256, 0, stream>>>(Qb, Kb, VTb, aohi, aolo);
        gemm_out<<<256, 256, 0, stream>>>(aohi, aolo, wbase + 6291456, wbase + 7340032, bo, out);
    } else {
        float* ws = (float*)d_ws;
        const size_t NELEM = (size_t)2 * SEQ * DMODEL;
        float* Qb = ws;
        float* Kb = ws + NELEM;
        float* Vb = ws + 2 * NELEM;
        float* AO = ws + 3 * NELEM;
        gemm_xwt<1><<<512, 256, 0, stream>>>(x, Wq, bq, Qb);
        gemm_xwt<1><<<512, 256, 0, stream>>>(x, Wk, bk, Kb);
        gemm_xwt<1><<<512, 256, 0, stream>>>(x, Wv, bv, Vb);
        attn_local_f32<<<2048, 256, 0, stream>>>(Qb, Kb, Vb, AO);
        gemm_xwt<0><<<512, 256, 0, stream>>>(AO, Wo, bo, out);
    }
}

// Round 7
// 146.695 us; speedup vs baseline: 1.8386x; 1.5072x over previous
//
#include <hip/hip_runtime.h>

// FixedSparseMultiHead: B=2, S=2048, D=1024, H=16, Hd=64, local band ±102.
// Round 7: fp16 single-product GEMMs (error budget: Q/K/V are stored bf16 for
// attention anyway -> projection GEMM error (fp16, ~2.5e-4) is 5x below the
// bf16 storage noise; out-proj fp16 adds ~8e-4 absmax, total ~1.5e-3 < 3.85e-3).
//   split5    : x,Wq,Wk,Wv,Wo -> fp16
//   gemm_qkv  : y=0/1: Q,K bf16 [B,H,S,64]; y=2: V^T bf16 [B,H,64,2176]
//   attn_mfma : bf16 banded attention (verified r4); AO -> fp16
//   gemm_out  : out = AO@Wo^T + bo, fp32
// GEMM core: round-6 K-major template (stage-first, 2-buf syncthreads, BK=32,
// conflict-free lane-linear LDS chunks), now 1 product -> 32 steps, 32KB LDS.
// Fallback fp32 path if ws_size < 80MB.

#define SEQ    2048
#define DMODEL 1024
#define NHEAD  16
#define HDIM   64
#define HALFW  102
#define BWMAX  240
#define VTS    2176    // padded V^T row stride (zeros beyond SEQ)

typedef unsigned short u16;
typedef __attribute__((ext_vector_type(8))) short bf16x8;
typedef __attribute__((ext_vector_type(8))) _Float16 f16x8;
typedef __attribute__((ext_vector_type(4))) float f32x4;

__device__ __forceinline__ u16 f2bf(float f) {
    unsigned u = __builtin_bit_cast(unsigned, f);
    unsigned r = (u + 0x7fffu + ((u >> 16) & 1u)) >> 16;   // RNE
    return (u16)r;
}
__device__ __forceinline__ float bf2f(u16 u) {
    return __builtin_bit_cast(float, ((unsigned)u) << 16);
}
__device__ __forceinline__ u16 f2h(float f) {
    return __builtin_bit_cast(u16, (_Float16)f);           // RNE
}

__device__ __forceinline__ void gload16(const void* g, void* l) {
    __builtin_amdgcn_global_load_lds(
        (const __attribute__((address_space(1))) void*)g,
        (__attribute__((address_space(3))) void*)l, 16, 0, 0);
}

// ---------------------------------------------------------------------------
// split: fp32 -> fp16.  y=0: x (4M elems); y=1..4: Wq/Wk/Wv/Wo (1M each).
// ---------------------------------------------------------------------------
__global__ __launch_bounds__(256) void split5(
    const float* __restrict__ x,  const float* __restrict__ wq,
    const float* __restrict__ wk, const float* __restrict__ wv,
    const float* __restrict__ wo,
    u16* __restrict__ xh, u16* __restrict__ wbase)
{
    const int y = blockIdx.y;
    const float* src; u16* dst; int nblk;
    switch (y) {
      case 0:  src = x;  dst = xh;              nblk = 4096; break;
      case 1:  src = wq; dst = wbase;           nblk = 1024; break;
      case 2:  src = wk; dst = wbase + 1048576; nblk = 1024; break;
      case 3:  src = wv; dst = wbase + 2097152; nblk = 1024; break;
      default: src = wo; dst = wbase + 3145728; nblk = 1024; break;
    }
    const int bx = blockIdx.x;
    if (bx >= nblk) return;
    const int i = (bx * 256 + threadIdx.x) * 4;
    const float4 v = *(const float4*)(src + i);
    ushort4 h;
    h.x = f2h(v.x); h.y = f2h(v.y); h.z = f2h(v.z); h.w = f2h(v.w);
    *(ushort4*)(dst + i) = h;
}

// ---------------------------------------------------------------------------
// MFMA GEMM core, fp16 single product: C[128x128] = A*B^T, K=1024, BK=32,
// 32 steps. 256 thr = 4 waves (2x2 of 64x64).
// LDS: 2 buffers x 8 chunks x [4 khalf][16 row][8 elem] per operand (chunk=1KB,
// lane-linear: gload_lds dst = chunk + ln*16B; fragment ds_read_b128 at
// chunk + ln*16B -> conflict-free; verified r5/r6).  32KB total.
// Schedule (r6 template): stage(buf0); sync;
//   loop t: { stage(buf^1, t+1); read 8 frags; 16 MFMA; sync; }
// ---------------------------------------------------------------------------
__device__ __forceinline__ void gemm_core(
    const u16* __restrict__ A, const u16* __restrict__ B,
    int m0, int n0, u16 (*sA)[4096], u16 (*sB)[4096], f32x4 acc[4][4])
{
    const int tid = threadIdx.x, ln = tid & 63, wave = tid >> 6;
    const int wm = wave >> 1, wn = wave & 1;
    const int srow = ln & 15, scol = (ln >> 4) * 8;

#pragma unroll
    for (int fm = 0; fm < 4; ++fm)
#pragma unroll
        for (int fn = 0; fn < 4; ++fn) acc[fm][fn] = (f32x4){0.f, 0.f, 0.f, 0.f};

    auto stage = [&](int buf, int k0) {
#pragma unroll
        for (int c = wave; c < 8; c += 4) {        // 2 chunks per wave per tile
            gload16(A + (size_t)(m0 + c * 16 + srow) * 1024 + k0 + scol, sA[buf] + c * 512);
            gload16(B + (size_t)(n0 + c * 16 + srow) * 1024 + k0 + scol, sB[buf] + c * 512);
        }
    };

    stage(0, 0);
    __syncthreads();

    for (int t = 0; t < 32; ++t) {
        const int cur = t & 1;
        if (t + 1 < 32) stage(cur ^ 1, (t + 1) << 5);

        f16x8 a[4], b[4];
#pragma unroll
        for (int f = 0; f < 4; ++f) {
            a[f] = *(const f16x8*)(sA[cur] + (wm * 4 + f) * 512 + ln * 8);
            b[f] = *(const f16x8*)(sB[cur] + (wn * 4 + f) * 512 + ln * 8);
        }
#pragma unroll
        for (int fm = 0; fm < 4; ++fm)
#pragma unroll
            for (int fn = 0; fn < 4; ++fn)
                acc[fm][fn] = __builtin_amdgcn_mfma_f32_16x16x32_f16(
                    a[fm], b[fn], acc[fm][fn], 0, 0, 0);
        __syncthreads();
    }
}

// ---------------------------------------------------------------------------
// Fused Q/K/V^T projection. y=0: Q bf16 [B,H,S,64]; y=1: K bf16 [B,H,S,64];
// y=2: V^T bf16 [B,H,64,VTS] via swapped operands (A=Wv, B=x).
// ---------------------------------------------------------------------------
__global__ __launch_bounds__(256) void gemm_qkv(
    const u16* __restrict__ xh, const u16* __restrict__ wbase,
    const float* __restrict__ bq, const float* __restrict__ bk,
    const float* __restrict__ bvv,
    u16* __restrict__ Qo, u16* __restrict__ Ko, u16* __restrict__ VTo)
{
    __shared__ u16 sA[2][4096], sB[2][4096];   // 32 KB
    const int y = blockIdx.y;
    const u16* W = wbase + (size_t)y * 1048576;

    const int bx = blockIdx.x;
    int m0, n0;
    if (y == 2) { m0 = (bx & 7) * 128; n0 = (bx >> 3) * 128; }          // m over D, n over 4096
    else { m0 = ((bx & 7) * 4 + (bx >> 6)) * 128; n0 = ((bx >> 3) & 7) * 128; }

    f32x4 acc[4][4];
    if (y == 2) gemm_core(W, xh, m0, n0, sA, sB, acc);
    else        gemm_core(xh, W, m0, n0, sA, sB, acc);

    const int tid = threadIdx.x, ln = tid & 63, wave = tid >> 6;
    const int wm = wave >> 1, wn = wave & 1;
    const int rl = ln & 15, kh = ln >> 4;

    if (y == 2) {
        // C[m=d-row][n=s-col] -> VT[(b*16+h)*64+hd][s], row stride VTS
#pragma unroll
        for (int fn = 0; fn < 4; ++fn) {
            const int n  = n0 + wn * 64 + fn * 16 + rl;   // 0..4095
            const int bb = n >> 11, s = n & (SEQ - 1);
#pragma unroll
            for (int fm = 0; fm < 4; ++fm)
#pragma unroll
                for (int r = 0; r < 4; ++r) {
                    const int m = m0 + wm * 64 + fm * 16 + kh * 4 + r;  // 0..1023
                    const float o = acc[fm][fn][r] + bvv[m];
                    const int row = (bb * NHEAD + (m >> 6)) * HDIM + (m & 63);
                    VTo[(size_t)row * VTS + s] = f2bf(o);
                }
        }
    } else {
        const float* bias = (y == 0) ? bq : bk;
        u16* Y = (y == 0) ? Qo : Ko;
        const int b = m0 >> 11;
#pragma unroll
        for (int fn = 0; fn < 4; ++fn) {
            const int n = n0 + wn * 64 + fn * 16 + rl;
            const float bb = bias[n];
            const int h = n >> 6, hd = n & 63;
#pragma unroll
            for (int fm = 0; fm < 4; ++fm)
#pragma unroll
                for (int r = 0; r < 4; ++r) {
                    const int m = m0 + wm * 64 + fm * 16 + kh * 4 + r;
                    const int s = m & (SEQ - 1);
                    Y[((size_t)(b * NHEAD + h) * SEQ + s) * HDIM + hd] =
                        f2bf(acc[fm][fn][r] + bb);
                }
        }
    }
}

// Final projection: out = AO@Wo^T + bo, fp32 out. A=AO fp16, B=Wo fp16.
__global__ __launch_bounds__(256) void gemm_out(
    const u16* __restrict__ A, const u16* __restrict__ B,
    const float* __restrict__ bias, float* __restrict__ Y)
{
    __shared__ u16 sA[2][4096], sB[2][4096];   // 32 KB
    const int bx = blockIdx.x;
    const int mt = (bx & 7) * 4 + (bx >> 6);
    const int nt = (bx >> 3) & 7;
    const int m0 = mt * 128, n0 = nt * 128;

    f32x4 acc[4][4];
    gemm_core(A, B, m0, n0, sA, sB, acc);

    const int tid = threadIdx.x, ln = tid & 63, wave = tid >> 6;
    const int wm = wave >> 1, wn = wave & 1;
    const int rl = ln & 15, kh = ln >> 4;
#pragma unroll
    for (int fn = 0; fn < 4; ++fn) {
        const int n = n0 + wn * 64 + fn * 16 + rl;
        const float bb = bias[n];
#pragma unroll
        for (int fm = 0; fm < 4; ++fm)
#pragma unroll
            for (int r = 0; r < 4; ++r) {
                const int m = m0 + wm * 64 + fm * 16 + kh * 4 + r;
                Y[(size_t)m * DMODEL + n] = acc[fm][fn][r] + bb;
            }
    }
}

// ---------------------------------------------------------------------------
// MFMA banded attention (r4-verified structure). Epilogue now writes AO fp16.
// ---------------------------------------------------------------------------
__global__ __launch_bounds__(256) void attn_mfma(
    const u16* __restrict__ Q, const u16* __restrict__ K,
    const u16* __restrict__ VT, u16* __restrict__ aoh)
{
    __shared__ u16 P_lds[4][16][232];   // 232-elem stride: 2-way banks (free)

    const int tid = threadIdx.x, ln = tid & 63, wv = tid >> 6;
    const int bx0 = blockIdx.x;
    const int asg = (bx0 & 7) * 128 + (bx0 >> 3);   // 1024 = 8 XCD * 128
    const int bh  = asg >> 5;
    const int qt  = asg & 31;
    const int b   = bh >> 4, h = bh & 15;
    const int q0  = qt * 64 + wv * 16;
    const int jmin = (q0 >= 104) ? (q0 - 104) : 0;   // == 0 (mod 8)

    const u16* Qbh  = Q  + (size_t)bh * SEQ * HDIM;
    const u16* Kbh  = K  + (size_t)bh * SEQ * HDIM;
    const u16* VTbh = VT + (size_t)bh * HDIM * VTS;

    const int lr = ln & 15, lk = ln >> 4;

    const bf16x8 qf0 = *(const bf16x8*)(Qbh + (size_t)(q0 + lr) * HDIM + lk * 8);
    const bf16x8 qf1 = *(const bf16x8*)(Qbh + (size_t)(q0 + lr) * HDIM + 32 + lk * 8);

    // ---- QK^T: 14 tiles x 2 MFMA ----
    f32x4 sc[14];
#pragma unroll
    for (int t = 0; t < 14; ++t) {
        const int j  = jmin + t * 16 + lr;
        const int jc = min(j, SEQ - 1);          // clamped load; masked below
        const u16* kp = Kbh + (size_t)jc * HDIM + lk * 8;
        const bf16x8 k0 = *(const bf16x8*)kp;
        const bf16x8 k1 = *(const bf16x8*)(kp + 32);
        f32x4 a = (f32x4){0.f, 0.f, 0.f, 0.f};
        a = __builtin_amdgcn_mfma_f32_16x16x32_bf16(qf0, k0, a, 0, 0, 0);
        a = __builtin_amdgcn_mfma_f32_16x16x32_bf16(qf1, k1, a, 0, 0, 0);
        sc[t] = a;
    }

    // ---- masked softmax, per C-row r (16-lane group shares a row) ----
    float lrow[4];
#pragma unroll
    for (int r = 0; r < 4; ++r) {
        const int i = q0 + lk * 4 + r;
        float mx = -3.0e38f;
#pragma unroll
        for (int t = 0; t < 14; ++t) {
            const int j = jmin + t * 16 + lr;
            float v = sc[t][r] * 0.125f;
            const bool ok = (j >= i - HALFW) && (j <= i + HALFW) && (j < SEQ);
            v = ok ? v : -3.0e38f;
            sc[t][r] = v;
            mx = fmaxf(mx, v);
        }
#pragma unroll
        for (int off = 8; off > 0; off >>= 1) mx = fmaxf(mx, __shfl_xor(mx, off));
        float sum = 0.f;
#pragma unroll
        for (int t = 0; t < 14; ++t) {
            const float p = __expf(sc[t][r] - mx);   // masked -> exactly 0
            sum += p;
            P_lds[wv][lk * 4 + r][t * 16 + lr] = f2bf(p);
        }
#pragma unroll
        for (int off = 8; off > 0; off >>= 1) sum += __shfl_xor(sum, off);
        lrow[r] = sum;
    }
    // same-wave LDS write->read; compiler inserts lgkmcnt waits

    // ---- PV: 7 k-chunks x 4 d-tiles, aligned unclamped V^T loads ----
    f32x4 ao[4];
#pragma unroll
    for (int nt = 0; nt < 4; ++nt) ao[nt] = (f32x4){0.f, 0.f, 0.f, 0.f};
#pragma unroll
    for (int kc = 0; kc < 7; ++kc) {
        const bf16x8 pf = *(const bf16x8*)&P_lds[wv][lr][kc * 32 + lk * 8];
        const int jb = jmin + kc * 32 + lk * 8;   // 16B aligned, < VTS
#pragma unroll
        for (int nt = 0; nt < 4; ++nt) {
            const bf16x8 vf = *(const bf16x8*)(VTbh + (size_t)(nt * 16 + lr) * VTS + jb);
            ao[nt] = __builtin_amdgcn_mfma_f32_16x16x32_bf16(pf, vf, ao[nt], 0, 0, 0);
        }
    }

    // ---- epilogue: AO -> fp16 [4096][1024] ----
#pragma unroll
    for (int nt = 0; nt < 4; ++nt)
#pragma unroll
        for (int r = 0; r < 4; ++r) {
            const int i = q0 + lk * 4 + r;
            const float o = ao[nt][r] / lrow[r];
            aoh[((size_t)b * SEQ + i) * DMODEL + h * HDIM + nt * 16 + lr] = f2h(o);
        }
}

// ---------------------------------------------------------------------------
// Round-1 fp32 path (fallback only).
// ---------------------------------------------------------------------------
template<int QKV>
__global__ __launch_bounds__(256) void gemm_xwt(
    const float* __restrict__ X, const float* __restrict__ W,
    const float* __restrict__ bias, float* __restrict__ Y)
{
    __shared__ float As[16][132];
    __shared__ float Bs[16][68];
    const int tid = threadIdx.x;
    const int bx  = blockIdx.x;
    const int n0  = (bx & 15) * 64;
    const int m0  = (bx >> 4) * 128;
    const int ty  = tid >> 4, tx = tid & 15;
    float acc[8][4];
#pragma unroll
    for (int r = 0; r < 8; ++r)
#pragma unroll
        for (int c = 0; c < 4; ++c) acc[r][c] = 0.f;
    const int lrow = tid >> 2, lkq = (tid & 3) * 4;
    for (int k0 = 0; k0 < DMODEL; k0 += 16) {
        float4 a0 = *(const float4*)(X + (size_t)(m0 + lrow)      * DMODEL + k0 + lkq);
        float4 a1 = *(const float4*)(X + (size_t)(m0 + lrow + 64) * DMODEL + k0 + lkq);
        float4 b0 = *(const float4*)(W + (size_t)(n0 + lrow)      * DMODEL + k0 + lkq);
        __syncthreads();
        As[lkq + 0][lrow] = a0.x; As[lkq + 1][lrow] = a0.y;
        As[lkq + 2][lrow] = a0.z; As[lkq + 3][lrow] = a0.w;
        As[lkq + 0][lrow + 64] = a1.x; As[lkq + 1][lrow + 64] = a1.y;
        As[lkq + 2][lrow + 64] = a1.z; As[lkq + 3][lrow + 64] = a1.w;
        Bs[lkq + 0][lrow] = b0.x; Bs[lkq + 1][lrow] = b0.y;
        Bs[lkq + 2][lrow] = b0.z; Bs[lkq + 3][lrow] = b0.w;
        __syncthreads();
#pragma unroll
        for (int k = 0; k < 16; ++k) {
            float4 av0 = *(const float4*)&As[k][ty * 8];
            float4 av1 = *(const float4*)&As[k][ty * 8 + 4];
            float4 bv  = *(const float4*)&Bs[k][tx * 4];
            float a[8] = {av0.x, av0.y, av0.z, av0.w, av1.x, av1.y, av1.z, av1.w};
            float bb[4] = {bv.x, bv.y, bv.z, bv.w};
#pragma unroll
            for (int r = 0; r < 8; ++r)
#pragma unroll
                for (int c = 0; c < 4; ++c) acc[r][c] += a[r] * bb[c];
        }
    }
    const float4 bb = *(const float4*)(bias + n0 + tx * 4);
    if (QKV) {
        const int b = m0 >> 11, h = n0 >> 6;
#pragma unroll
        for (int r = 0; r < 8; ++r) {
            const int m = m0 + ty * 8 + r, ss = m & (SEQ - 1);
            float4 o = {acc[r][0] + bb.x, acc[r][1] + bb.y, acc[r][2] + bb.z, acc[r][3] + bb.w};
            *(float4*)(Y + ((size_t)(b * NHEAD + h) * SEQ + ss) * HDIM + tx * 4) = o;
        }
    } else {
#pragma unroll
        for (int r = 0; r < 8; ++r) {
            const int m = m0 + ty * 8 + r;
            float4 o = {acc[r][0] + bb.x, acc[r][1] + bb.y, acc[r][2] + bb.z, acc[r][3] + bb.w};
            *(float4*)(Y + (size_t)m * DMODEL + n0 + tx * 4) = o;
        }
    }
}

__global__ __launch_bounds__(256) void attn_local_f32(
    const float* __restrict__ Q, const float* __restrict__ K,
    const float* __restrict__ V, float* __restrict__ O)
{
    __shared__ float ssc[32][BWMAX];
    const int tid = threadIdx.x;
    const int bx0 = blockIdx.x;
    const int bx  = (bx0 & 7) * 256 + (bx0 >> 3);
    const int qt  = bx & 63;
    const int h   = (bx >> 6) & 15;
    const int b   = bx >> 10;
    const int i0  = qt * 32;
    const int jmin = max(0, i0 - HALFW);
    const int jmax = min(SEQ - 1, i0 + 31 + HALFW);
    const int BWt  = jmax - jmin + 1;
    const float* Qbh = Q + (size_t)(b * NHEAD + h) * SEQ * HDIM;
    const float* Kbh = K + (size_t)(b * NHEAD + h) * SEQ * HDIM;
    const float* Vbh = V + (size_t)(b * NHEAD + h) * SEQ * HDIM;
    const int jj = tid;
    if (jj < BWt) {
        float acc[32];
#pragma unroll
        for (int i = 0; i < 32; ++i) acc[i] = 0.f;
        const float* kp = Kbh + (size_t)(jmin + jj) * HDIM;
        for (int d0 = 0; d0 < HDIM; d0 += 4) {
            const float4 kv = *(const float4*)(kp + d0);
#pragma unroll
            for (int i = 0; i < 32; ++i) {
                const float4 qv = *(const float4*)(Qbh + (size_t)(i0 + i) * HDIM + d0);
                acc[i] += qv.x * kv.x + qv.y * kv.y + qv.z * kv.z + qv.w * kv.w;
            }
        }
#pragma unroll
        for (int i = 0; i < 32; ++i) ssc[i][jj] = acc[i] * 0.125f;
    }
    __syncthreads();
    const int wv = tid >> 6, ln = tid & 63;
    float rs[8];
#pragma unroll
    for (int r = 0; r < 8; ++r) {
        const int i  = wv * 8 + r;
        const int qi = i0 + i;
        const int lo = max(0, qi - HALFW) - jmin;
        const int hi = min(SEQ - 1, qi + HALFW) - jmin;
        float m = -1e30f;
#pragma unroll
        for (int c = 0; c < 4; ++c) {
            const int j = ln + 64 * c;
            if (j >= lo && j <= hi) m = fmaxf(m, ssc[i][j]);
        }
#pragma unroll
        for (int off = 32; off > 0; off >>= 1) m = fmaxf(m, __shfl_xor(m, off));
        float sum = 0.f;
#pragma unroll
        for (int c = 0; c < 4; ++c) {
            const int j = ln + 64 * c;
            if (j < BWt) {
                float p = 0.f;
                if (j >= lo && j <= hi) p = __expf(ssc[i][j] - m);
                ssc[i][j] = p;
                sum += p;
            }
        }
#pragma unroll
        for (int off = 32; off > 0; off >>= 1) sum += __shfl_xor(sum, off);
        rs[r] = sum;
    }
    float oa[8];
#pragma unroll
    for (int r = 0; r < 8; ++r) oa[r] = 0.f;
    int jq = 0;
    for (; jq + 4 <= BWt; jq += 4) {
        const float v0 = Vbh[(size_t)(jmin + jq + 0) * HDIM + ln];
        const float v1 = Vbh[(size_t)(jmin + jq + 1) * HDIM + ln];
        const float v2 = Vbh[(size_t)(jmin + jq + 2) * HDIM + ln];
        const float v3 = Vbh[(size_t)(jmin + jq + 3) * HDIM + ln];
#pragma unroll
        for (int r = 0; r < 8; ++r) {
            const float4 p4 = *(const float4*)&ssc[wv * 8 + r][jq];
            oa[r] += p4.x * v0 + p4.y * v1 + p4.z * v2 + p4.w * v3;
        }
    }
    for (; jq < BWt; ++jq) {
        const float v0 = Vbh[(size_t)(jmin + jq) * HDIM + ln];
#pragma unroll
        for (int r = 0; r < 8; ++r) oa[r] += ssc[wv * 8 + r][jq] * v0;
    }
#pragma unroll
    for (int r = 0; r < 8; ++r) {
        const int i = i0 + wv * 8 + r;
        O[((size_t)b * SEQ + i) * DMODEL + h * HDIM + ln] = oa[r] / rs[r];
    }
}

// ---------------------------------------------------------------------------
extern "C" void kernel_launch(void* const* d_in, const int* in_sizes, int n_in,
                              void* d_out, int out_size, void* d_ws, size_t ws_size,
                              hipStream_t stream) {
    const float* x  = (const float*)d_in[0];
    const float* Wq = (const float*)d_in[1];
    const float* bq = (const float*)d_in[2];
    const float* Wk = (const float*)d_in[3];
    const float* bk = (const float*)d_in[4];
    const float* Wv = (const float*)d_in[5];
    const float* bv = (const float*)d_in[6];
    const float* Wo = (const float*)d_in[7];
    const float* bo = (const float*)d_in[8];

    float* out = (float*)d_out;

    const size_t REQUIRED = (size_t)80 * 1024 * 1024;
    if (ws_size >= REQUIRED) {
        const size_t M4 = 4194304;                       // 4M u16 = 8MB
        const size_t VT_ELEMS = (size_t)32 * HDIM * VTS; // 4,456,448 u16
        u16* Qb    = (u16*)d_ws;                         // bf16
        u16* Kb    = Qb + M4;                            // bf16
        u16* VTb   = Kb + M4;                            // bf16, padded rows
        u16* aoh   = VTb + VT_ELEMS;                     // fp16
        u16* xh    = aoh + M4;                           // fp16
        u16* wbase = xh + M4;                            // fp16: Wq,Wk,Wv,Wo (4x1M)

        hipMemsetAsync(VTb, 0, VT_ELEMS * sizeof(u16), stream);  // zero pad cols
        split5<<<dim3(4096, 5), 256, 0, stream>>>(x, Wq, Wk, Wv, Wo, xh, wbase);
        gemm_qkv<<<dim3(256, 3), 256, 0, stream>>>(xh, wbase, bq, bk, bv, Qb, Kb, VTb);
        attn_mfma<<<1024, 256, 0, stream>>>(Qb, Kb, VTb, aoh);
        gemm_out<<<256, 256, 0, stream>>>(aoh, wbase + 3145728, bo, out);
    } else {
        float* ws = (float*)d_ws;
        const size_t NELEM = (size_t)2 * SEQ * DMODEL;
        float* Qb = ws;
        float* Kb = ws + NELEM;
        float* Vb = ws + 2 * NELEM;
        float* AO = ws + 3 * NELEM;
        gemm_xwt<1><<<512, 256, 0, stream>>>(x, Wq, bq, Qb);
        gemm_xwt<1><<<512, 256, 0, stream>>>(x, Wk, bk, Kb);
        gemm_xwt<1><<<512, 256, 0, stream>>>(x, Wv, bv, Vb);
        attn_local_f32<<<2048, 256, 0, stream>>>(Qb, Kb, Vb, AO);
        gemm_xwt<0><<<512, 256, 0, stream>>>(AO, Wo, bo, out);
    }
}

// Round 8
// 124.347 us; speedup vs baseline: 2.1690x; 1.1797x over previous
//
#include <hip/hip_runtime.h>

// FixedSparseMultiHead: B=2, S=2048, D=1024, H=16, Hd=64, local band ±102.
// Round 8: counted-vmcnt GEMM pipeline, ONE barrier per K-step.
//   5 LDS buffers, prefetch distance 3:
//     step t: stage(t+3); s_waitcnt vmcnt(12); s_barrier; ds_read buf[t%5]; MFMA
//   Safety: vmcnt(12)+barrier => all waves' stage-t loads landed before reads;
//   stage(t+3) overwrites buf read at t-2, all reads of which complete before
//   barrier(t-1) (MFMA data-dep), which precedes stage(t+3). 80KB LDS, 2 blk/CU.
// Everything else = round 7 (fp16 single-product GEMMs, bf16 attention).
// Fallback fp32 path if ws_size < 80MB.

#define SEQ    2048
#define DMODEL 1024
#define NHEAD  16
#define HDIM   64
#define HALFW  102
#define BWMAX  240
#define VTS    2176    // padded V^T row stride (zeros beyond SEQ)

typedef unsigned short u16;
typedef __attribute__((ext_vector_type(8))) short bf16x8;
typedef __attribute__((ext_vector_type(8))) _Float16 f16x8;
typedef __attribute__((ext_vector_type(4))) float f32x4;

#define VMW12() asm volatile("s_waitcnt vmcnt(12)" ::: "memory")
#define VMW8()  asm volatile("s_waitcnt vmcnt(8)"  ::: "memory")
#define VMW4()  asm volatile("s_waitcnt vmcnt(4)"  ::: "memory")
#define VMW0()  asm volatile("s_waitcnt vmcnt(0)"  ::: "memory")
#define BARR()  __builtin_amdgcn_s_barrier()
#define CFENCE() asm volatile("" ::: "memory")

__device__ __forceinline__ u16 f2bf(float f) {
    unsigned u = __builtin_bit_cast(unsigned, f);
    unsigned r = (u + 0x7fffu + ((u >> 16) & 1u)) >> 16;   // RNE
    return (u16)r;
}
__device__ __forceinline__ float bf2f(u16 u) {
    return __builtin_bit_cast(float, ((unsigned)u) << 16);
}
__device__ __forceinline__ u16 f2h(float f) {
    return __builtin_bit_cast(u16, (_Float16)f);           // RNE
}

__device__ __forceinline__ void gload16(const void* g, void* l) {
    __builtin_amdgcn_global_load_lds(
        (const __attribute__((address_space(1))) void*)g,
        (__attribute__((address_space(3))) void*)l, 16, 0, 0);
}

// ---------------------------------------------------------------------------
// split: fp32 -> fp16.  y=0: x (4M elems); y=1..4: Wq/Wk/Wv/Wo (1M each).
// ---------------------------------------------------------------------------
__global__ __launch_bounds__(256) void split5(
    const float* __restrict__ x,  const float* __restrict__ wq,
    const float* __restrict__ wk, const float* __restrict__ wv,
    const float* __restrict__ wo,
    u16* __restrict__ xh, u16* __restrict__ wbase)
{
    const int y = blockIdx.y;
    const float* src; u16* dst; int nblk;
    switch (y) {
      case 0:  src = x;  dst = xh;              nblk = 4096; break;
      case 1:  src = wq; dst = wbase;           nblk = 1024; break;
      case 2:  src = wk; dst = wbase + 1048576; nblk = 1024; break;
      case 3:  src = wv; dst = wbase + 2097152; nblk = 1024; break;
      default: src = wo; dst = wbase + 3145728; nblk = 1024; break;
    }
    const int bx = blockIdx.x;
    if (bx >= nblk) return;
    const int i = (bx * 256 + threadIdx.x) * 4;
    const float4 v = *(const float4*)(src + i);
    ushort4 h;
    h.x = f2h(v.x); h.y = f2h(v.y); h.z = f2h(v.z); h.w = f2h(v.w);
    *(ushort4*)(dst + i) = h;
}

// ---------------------------------------------------------------------------
// MFMA GEMM core, fp16: C[128x128] = A*B^T, K=1024, BK=32, 32 steps.
// 256 thr = 4 waves (2x2 of 64x64).
// LDS: 5 buffers x 8 chunks x [4 khalf][16 row][8 elem] per operand
//   (chunk = 1KB, lane-linear -> conflict-free; verified r5-r7). 80 KB.
// Schedule: prologue stage(0,1,2); per step: stage(t+3), counted vmcnt,
//   ONE s_barrier, ds_read + 16 MFMA. Tail drains 12/8/4/0.
// ---------------------------------------------------------------------------
__device__ __forceinline__ void gemm_core(
    const u16* __restrict__ A, const u16* __restrict__ B,
    int m0, int n0, u16 (*sA)[4096], u16 (*sB)[4096], f32x4 acc[4][4])
{
    const int tid = threadIdx.x, ln = tid & 63, wave = tid >> 6;
    const int wm = wave >> 1, wn = wave & 1;
    const int srow = ln & 15, scol = (ln >> 4) * 8;

#pragma unroll
    for (int fm = 0; fm < 4; ++fm)
#pragma unroll
        for (int fn = 0; fn < 4; ++fn) acc[fm][fn] = (f32x4){0.f, 0.f, 0.f, 0.f};

    auto stage = [&](int s) {
        if (s >= 32) return;
        const int buf = s % 5;
        const int k0 = s << 5;
#pragma unroll
        for (int c = wave; c < 8; c += 4) {        // 2 chunks per wave per tile
            gload16(A + (size_t)(m0 + c * 16 + srow) * 1024 + k0 + scol, sA[buf] + c * 512);
            gload16(B + (size_t)(n0 + c * 16 + srow) * 1024 + k0 + scol, sB[buf] + c * 512);
        }
    };

    stage(0); stage(1); stage(2);

    int buf = 0;
    for (int t = 0; t < 32; ++t) {
        stage(t + 3);
        if (t < 29)       VMW12();   // stages t+1..t+3 in flight (4 loads each)
        else if (t == 29) VMW8();
        else if (t == 30) VMW4();
        else              VMW0();
        BARR();
        CFENCE();

        f16x8 a[4], b[4];
#pragma unroll
        for (int f = 0; f < 4; ++f) {
            a[f] = *(const f16x8*)(sA[buf] + (wm * 4 + f) * 512 + ln * 8);
            b[f] = *(const f16x8*)(sB[buf] + (wn * 4 + f) * 512 + ln * 8);
        }
#pragma unroll
        for (int fm = 0; fm < 4; ++fm)
#pragma unroll
            for (int fn = 0; fn < 4; ++fn)
                acc[fm][fn] = __builtin_amdgcn_mfma_f32_16x16x32_f16(
                    a[fm], b[fn], acc[fm][fn], 0, 0, 0);
        buf = (buf == 4) ? 0 : buf + 1;
    }
}

// ---------------------------------------------------------------------------
// Fused Q/K/V^T projection. y=0: Q bf16 [B,H,S,64]; y=1: K bf16 [B,H,S,64];
// y=2: V^T bf16 [B,H,64,VTS] via swapped operands (A=Wv, B=x).
// ---------------------------------------------------------------------------
__global__ __launch_bounds__(256) void gemm_qkv(
    const u16* __restrict__ xh, const u16* __restrict__ wbase,
    const float* __restrict__ bq, const float* __restrict__ bk,
    const float* __restrict__ bvv,
    u16* __restrict__ Qo, u16* __restrict__ Ko, u16* __restrict__ VTo)
{
    __shared__ u16 sA[5][4096], sB[5][4096];   // 80 KB -> 2 blocks/CU
    const int y = blockIdx.y;
    const u16* W = wbase + (size_t)y * 1048576;

    const int bx = blockIdx.x;
    int m0, n0;
    if (y == 2) { m0 = (bx & 7) * 128; n0 = (bx >> 3) * 128; }          // m over D, n over 4096
    else { m0 = ((bx & 7) * 4 + (bx >> 6)) * 128; n0 = ((bx >> 3) & 7) * 128; }

    f32x4 acc[4][4];
    if (y == 2) gemm_core(W, xh, m0, n0, sA, sB, acc);
    else        gemm_core(xh, W, m0, n0, sA, sB, acc);

    const int tid = threadIdx.x, ln = tid & 63, wave = tid >> 6;
    const int wm = wave >> 1, wn = wave & 1;
    const int rl = ln & 15, kh = ln >> 4;

    if (y == 2) {
        // C[m=d-row][n=s-col] -> VT[(b*16+h)*64+hd][s], row stride VTS
#pragma unroll
        for (int fn = 0; fn < 4; ++fn) {
            const int n  = n0 + wn * 64 + fn * 16 + rl;   // 0..4095
            const int bb = n >> 11, s = n & (SEQ - 1);
#pragma unroll
            for (int fm = 0; fm < 4; ++fm)
#pragma unroll
                for (int r = 0; r < 4; ++r) {
                    const int m = m0 + wm * 64 + fm * 16 + kh * 4 + r;  // 0..1023
                    const float o = acc[fm][fn][r] + bvv[m];
                    const int row = (bb * NHEAD + (m >> 6)) * HDIM + (m & 63);
                    VTo[(size_t)row * VTS + s] = f2bf(o);
                }
        }
    } else {
        const float* bias = (y == 0) ? bq : bk;
        u16* Y = (y == 0) ? Qo : Ko;
        const int b = m0 >> 11;
#pragma unroll
        for (int fn = 0; fn < 4; ++fn) {
            const int n = n0 + wn * 64 + fn * 16 + rl;
            const float bb = bias[n];
            const int h = n >> 6, hd = n & 63;
#pragma unroll
            for (int fm = 0; fm < 4; ++fm)
#pragma unroll
                for (int r = 0; r < 4; ++r) {
                    const int m = m0 + wm * 64 + fm * 16 + kh * 4 + r;
                    const int s = m & (SEQ - 1);
                    Y[((size_t)(b * NHEAD + h) * SEQ + s) * HDIM + hd] =
                        f2bf(acc[fm][fn][r] + bb);
                }
        }
    }
}

// Final projection: out = AO@Wo^T + bo, fp32 out. A=AO fp16, B=Wo fp16.
__global__ __launch_bounds__(256) void gemm_out(
    const u16* __restrict__ A, const u16* __restrict__ B,
    const float* __restrict__ bias, float* __restrict__ Y)
{
    __shared__ u16 sA[5][4096], sB[5][4096];   // 80 KB
    const int bx = blockIdx.x;
    const int mt = (bx & 7) * 4 + (bx >> 6);
    const int nt = (bx >> 3) & 7;
    const int m0 = mt * 128, n0 = nt * 128;

    f32x4 acc[4][4];
    gemm_core(A, B, m0, n0, sA, sB, acc);

    const int tid = threadIdx.x, ln = tid & 63, wave = tid >> 6;
    const int wm = wave >> 1, wn = wave & 1;
    const int rl = ln & 15, kh = ln >> 4;
#pragma unroll
    for (int fn = 0; fn < 4; ++fn) {
        const int n = n0 + wn * 64 + fn * 16 + rl;
        const float bb = bias[n];
#pragma unroll
        for (int fm = 0; fm < 4; ++fm)
#pragma unroll
            for (int r = 0; r < 4; ++r) {
                const int m = m0 + wm * 64 + fm * 16 + kh * 4 + r;
                Y[(size_t)m * DMODEL + n] = acc[fm][fn][r] + bb;
            }
    }
}

// ---------------------------------------------------------------------------
// MFMA banded attention (r4-verified structure). Epilogue writes AO fp16.
// ---------------------------------------------------------------------------
__global__ __launch_bounds__(256) void attn_mfma(
    const u16* __restrict__ Q, const u16* __restrict__ K,
    const u16* __restrict__ VT, u16* __restrict__ aoh)
{
    __shared__ u16 P_lds[4][16][232];   // 232-elem stride: 2-way banks (free)

    const int tid = threadIdx.x, ln = tid & 63, wv = tid >> 6;
    const int bx0 = blockIdx.x;
    const int asg = (bx0 & 7) * 128 + (bx0 >> 3);   // 1024 = 8 XCD * 128
    const int bh  = asg >> 5;
    const int qt  = asg & 31;
    const int b   = bh >> 4, h = bh & 15;
    const int q0  = qt * 64 + wv * 16;
    const int jmin = (q0 >= 104) ? (q0 - 104) : 0;   // == 0 (mod 8)

    const u16* Qbh  = Q  + (size_t)bh * SEQ * HDIM;
    const u16* Kbh  = K  + (size_t)bh * SEQ * HDIM;
    const u16* VTbh = VT + (size_t)bh * HDIM * VTS;

    const int lr = ln & 15, lk = ln >> 4;

    const bf16x8 qf0 = *(const bf16x8*)(Qbh + (size_t)(q0 + lr) * HDIM + lk * 8);
    const bf16x8 qf1 = *(const bf16x8*)(Qbh + (size_t)(q0 + lr) * HDIM + 32 + lk * 8);

    // ---- QK^T: 14 tiles x 2 MFMA ----
    f32x4 sc[14];
#pragma unroll
    for (int t = 0; t < 14; ++t) {
        const int j  = jmin + t * 16 + lr;
        const int jc = min(j, SEQ - 1);          // clamped load; masked below
        const u16* kp = Kbh + (size_t)jc * HDIM + lk * 8;
        const bf16x8 k0 = *(const bf16x8*)kp;
        const bf16x8 k1 = *(const bf16x8*)(kp + 32);
        f32x4 a = (f32x4){0.f, 0.f, 0.f, 0.f};
        a = __builtin_amdgcn_mfma_f32_16x16x32_bf16(qf0, k0, a, 0, 0, 0);
        a = __builtin_amdgcn_mfma_f32_16x16x32_bf16(qf1, k1, a, 0, 0, 0);
        sc[t] = a;
    }

    // ---- masked softmax, per C-row r (16-lane group shares a row) ----
    float lrow[4];
#pragma unroll
    for (int r = 0; r < 4; ++r) {
        const int i = q0 + lk * 4 + r;
        float mx = -3.0e38f;
#pragma unroll
        for (int t = 0; t < 14; ++t) {
            const int j = jmin + t * 16 + lr;
            float v = sc[t][r] * 0.125f;
            const bool ok = (j >= i - HALFW) && (j <= i + HALFW) && (j < SEQ);
            v = ok ? v : -3.0e38f;
            sc[t][r] = v;
            mx = fmaxf(mx, v);
        }
#pragma unroll
        for (int off = 8; off > 0; off >>= 1) mx = fmaxf(mx, __shfl_xor(mx, off));
        float sum = 0.f;
#pragma unroll
        for (int t = 0; t < 14; ++t) {
            const float p = __expf(sc[t][r] - mx);   // masked -> exactly 0
            sum += p;
            P_lds[wv][lk * 4 + r][t * 16 + lr] = f2bf(p);
        }
#pragma unroll
        for (int off = 8; off > 0; off >>= 1) sum += __shfl_xor(sum, off);
        lrow[r] = sum;
    }
    // same-wave LDS write->read; compiler inserts lgkmcnt waits

    // ---- PV: 7 k-chunks x 4 d-tiles, aligned unclamped V^T loads ----
    f32x4 ao[4];
#pragma unroll
    for (int nt = 0; nt < 4; ++nt) ao[nt] = (f32x4){0.f, 0.f, 0.f, 0.f};
#pragma unroll
    for (int kc = 0; kc < 7; ++kc) {
        const bf16x8 pf = *(const bf16x8*)&P_lds[wv][lr][kc * 32 + lk * 8];
        const int jb = jmin + kc * 32 + lk * 8;   // 16B aligned, < VTS
#pragma unroll
        for (int nt = 0; nt < 4; ++nt) {
            const bf16x8 vf = *(const bf16x8*)(VTbh + (size_t)(nt * 16 + lr) * VTS + jb);
            ao[nt] = __builtin_amdgcn_mfma_f32_16x16x32_bf16(pf, vf, ao[nt], 0, 0, 0);
        }
    }

    // ---- epilogue: AO -> fp16 [4096][1024] ----
#pragma unroll
    for (int nt = 0; nt < 4; ++nt)
#pragma unroll
        for (int r = 0; r < 4; ++r) {
            const int i = q0 + lk * 4 + r;
            const float o = ao[nt][r] / lrow[r];
            aoh[((size_t)b * SEQ + i) * DMODEL + h * HDIM + nt * 16 + lr] = f2h(o);
        }
}

// ---------------------------------------------------------------------------
// Round-1 fp32 path (fallback only).
// ---------------------------------------------------------------------------
template<int QKV>
__global__ __launch_bounds__(256) void gemm_xwt(
    const float* __restrict__ X, const float* __restrict__ W,
    const float* __restrict__ bias, float* __restrict__ Y)
{
    __shared__ float As[16][132];
    __shared__ float Bs[16][68];
    const int tid = threadIdx.x;
    const int bx  = blockIdx.x;
    const int n0  = (bx & 15) * 64;
    const int m0  = (bx >> 4) * 128;
    const int ty  = tid >> 4, tx = tid & 15;
    float acc[8][4];
#pragma unroll
    for (int r = 0; r < 8; ++r)
#pragma unroll
        for (int c = 0; c < 4; ++c) acc[r][c] = 0.f;
    const int lrow = tid >> 2, lkq = (tid & 3) * 4;
    for (int k0 = 0; k0 < DMODEL; k0 += 16) {
        float4 a0 = *(const float4*)(X + (size_t)(m0 + lrow)      * DMODEL + k0 + lkq);
        float4 a1 = *(const float4*)(X + (size_t)(m0 + lrow + 64) * DMODEL + k0 + lkq);
        float4 b0 = *(const float4*)(W + (size_t)(n0 + lrow)      * DMODEL + k0 + lkq);
        __syncthreads();
        As[lkq + 0][lrow] = a0.x; As[lkq + 1][lrow] = a0.y;
        As[lkq + 2][lrow] = a0.z; As[lkq + 3][lrow] = a0.w;
        As[lkq + 0][lrow + 64] = a1.x; As[lkq + 1][lrow + 64] = a1.y;
        As[lkq + 2][lrow + 64] = a1.z; As[lkq + 3][lrow + 64] = a1.w;
        Bs[lkq + 0][lrow] = b0.x; Bs[lkq + 1][lrow] = b0.y;
        Bs[lkq + 2][lrow] = b0.z; Bs[lkq + 3][lrow] = b0.w;
        __syncthreads();
#pragma unroll
        for (int k = 0; k < 16; ++k) {
            float4 av0 = *(const float4*)&As[k][ty * 8];
            float4 av1 = *(const float4*)&As[k][ty * 8 + 4];
            float4 bv  = *(const float4*)&Bs[k][tx * 4];
            float a[8] = {av0.x, av0.y, av0.z, av0.w, av1.x, av1.y, av1.z, av1.w};
            float bb[4] = {bv.x, bv.y, bv.z, bv.w};
#pragma unroll
            for (int r = 0; r < 8; ++r)
#pragma unroll
                for (int c = 0; c < 4; ++c) acc[r][c] += a[r] * bb[c];
        }
    }
    const float4 bb = *(const float4*)(bias + n0 + tx * 4);
    if (QKV) {
        const int b = m0 >> 11, h = n0 >> 6;
#pragma unroll
        for (int r = 0; r < 8; ++r) {
            const int m = m0 + ty * 8 + r, ss = m & (SEQ - 1);
            float4 o = {acc[r][0] + bb.x, acc[r][1] + bb.y, acc[r][2] + bb.z, acc[r][3] + bb.w};
            *(float4*)(Y + ((size_t)(b * NHEAD + h) * SEQ + ss) * HDIM + tx * 4) = o;
        }
    } else {
#pragma unroll
        for (int r = 0; r < 8; ++r) {
            const int m = m0 + ty * 8 + r;
            float4 o = {acc[r][0] + bb.x, acc[r][1] + bb.y, acc[r][2] + bb.z, acc[r][3] + bb.w};
            *(float4*)(Y + (size_t)m * DMODEL + n0 + tx * 4) = o;
        }
    }
}

__global__ __launch_bounds__(256) void attn_local_f32(
    const float* __restrict__ Q, const float* __restrict__ K,
    const float* __restrict__ V, float* __restrict__ O)
{
    __shared__ float ssc[32][BWMAX];
    const int tid = threadIdx.x;
    const int bx0 = blockIdx.x;
    const int bx  = (bx0 & 7) * 256 + (bx0 >> 3);
    const int qt  = bx & 63;
    const int h   = (bx >> 6) & 15;
    const int b   = bx >> 10;
    const int i0  = qt * 32;
    const int jmin = max(0, i0 - HALFW);
    const int jmax = min(SEQ - 1, i0 + 31 + HALFW);
    const int BWt  = jmax - jmin + 1;
    const float* Qbh = Q + (size_t)(b * NHEAD + h) * SEQ * HDIM;
    const float* Kbh = K + (size_t)(b * NHEAD + h) * SEQ * HDIM;
    const float* Vbh = V + (size_t)(b * NHEAD + h) * SEQ * HDIM;
    const int jj = tid;
    if (jj < BWt) {
        float acc[32];
#pragma unroll
        for (int i = 0; i < 32; ++i) acc[i] = 0.f;
        const float* kp = Kbh + (size_t)(jmin + jj) * HDIM;
        for (int d0 = 0; d0 < HDIM; d0 += 4) {
            const float4 kv = *(const float4*)(kp + d0);
#pragma unroll
            for (int i = 0; i < 32; ++i) {
                const float4 qv = *(const float4*)(Qbh + (size_t)(i0 + i) * HDIM + d0);
                acc[i] += qv.x * kv.x + qv.y * kv.y + qv.z * kv.z + qv.w * kv.w;
            }
        }
#pragma unroll
        for (int i = 0; i < 32; ++i) ssc[i][jj] = acc[i] * 0.125f;
    }
    __syncthreads();
    const int wv = tid >> 6, ln = tid & 63;
    float rs[8];
#pragma unroll
    for (int r = 0; r < 8; ++r) {
        const int i  = wv * 8 + r;
        const int qi = i0 + i;
        const int lo = max(0, qi - HALFW) - jmin;
        const int hi = min(SEQ - 1, qi + HALFW) - jmin;
        float m = -1e30f;
#pragma unroll
        for (int c = 0; c < 4; ++c) {
            const int j = ln + 64 * c;
            if (j >= lo && j <= hi) m = fmaxf(m, ssc[i][j]);
        }
#pragma unroll
        for (int off = 32; off > 0; off >>= 1) m = fmaxf(m, __shfl_xor(m, off));
        float sum = 0.f;
#pragma unroll
        for (int c = 0; c < 4; ++c) {
            const int j = ln + 64 * c;
            if (j < BWt) {
                float p = 0.f;
                if (j >= lo && j <= hi) p = __expf(ssc[i][j] - m);
                ssc[i][j] = p;
                sum += p;
            }
        }
#pragma unroll
        for (int off = 32; off > 0; off >>= 1) sum += __shfl_xor(sum, off);
        rs[r] = sum;
    }
    float oa[8];
#pragma unroll
    for (int r = 0; r < 8; ++r) oa[r] = 0.f;
    int jq = 0;
    for (; jq + 4 <= BWt; jq += 4) {
        const float v0 = Vbh[(size_t)(jmin + jq + 0) * HDIM + ln];
        const float v1 = Vbh[(size_t)(jmin + jq + 1) * HDIM + ln];
        const float v2 = Vbh[(size_t)(jmin + jq + 2) * HDIM + ln];
        const float v3 = Vbh[(size_t)(jmin + jq + 3) * HDIM + ln];
#pragma unroll
        for (int r = 0; r < 8; ++r) {
            const float4 p4 = *(const float4*)&ssc[wv * 8 + r][jq];
            oa[r] += p4.x * v0 + p4.y * v1 + p4.z * v2 + p4.w * v3;
        }
    }
    for (; jq < BWt; ++jq) {
        const float v0 = Vbh[(size_t)(jmin + jq) * HDIM + ln];
#pragma unroll
        for (int r = 0; r < 8; ++r) oa[r] += ssc[wv * 8 + r][jq] * v0;
    }
#pragma unroll
    for (int r = 0; r < 8; ++r) {
        const int i = i0 + wv * 8 + r;
        O[((size_t)b * SEQ + i) * DMODEL + h * HDIM + ln] = oa[r] / rs[r];
    }
}

// ---------------------------------------------------------------------------
extern "C" void kernel_launch(void* const* d_in, const int* in_sizes, int n_in,
                              void* d_out, int out_size, void* d_ws, size_t ws_size,
                              hipStream_t stream) {
    const float* x  = (const float*)d_in[0];
    const float* Wq = (const float*)d_in[1];
    const float* bq = (const float*)d_in[2];
    const float* Wk = (const float*)d_in[3];
    const float* bk = (const float*)d_in[4];
    const float* Wv = (const float*)d_in[5];
    const float* bv = (const float*)d_in[6];
    const float* Wo = (const float*)d_in[7];
    const float* bo = (const float*)d_in[8];

    float* out = (float*)d_out;

    const size_t REQUIRED = (size_t)80 * 1024 * 1024;
    if (ws_size >= REQUIRED) {
        const size_t M4 = 4194304;                       // 4M u16 = 8MB
        const size_t VT_ELEMS = (size_t)32 * HDIM * VTS; // 4,456,448 u16
        u16* Qb    = (u16*)d_ws;                         // bf16
        u16* Kb    = Qb + M4;                            // bf16
        u16* VTb   = Kb + M4;                            // bf16, padded rows
        u16* aoh   = VTb + VT_ELEMS;                     // fp16
        u16* xh    = aoh + M4;                           // fp16
        u16* wbase = xh + M4;                            // fp16: Wq,Wk,Wv,Wo (4x1M)

        hipMemsetAsync(VTb, 0, VT_ELEMS * sizeof(u16), stream);  // zero pad cols
        split5<<<dim3(4096, 5), 256, 0, stream>>>(x, Wq, Wk, Wv, Wo, xh, wbase);
        gemm_qkv<<<dim3(256, 3), 256, 0, stream>>>(xh, wbase, bq, bk, bv, Qb, Kb, VTb);
        attn_mfma<<<1024, 256, 0, stream>>>(Qb, Kb, VTb, aoh);
        gemm_out<<<256, 256, 0, stream>>>(aoh, wbase + 3145728, bo, out);
    } else {
        float* ws = (float*)d_ws;
        const size_t NELEM = (size_t)2 * SEQ * DMODEL;
        float* Qb = ws;
        float* Kb = ws + NELEM;
        float* Vb = ws + 2 * NELEM;
        float* AO = ws + 3 * NELEM;
        gemm_xwt<1><<<512, 256, 0, stream>>>(x, Wq, bq, Qb);
        gemm_xwt<1><<<512, 256, 0, stream>>>(x, Wk, bk, Kb);
        gemm_xwt<1><<<512, 256, 0, stream>>>(x, Wv, bv, Vb);
        attn_local_f32<<<2048, 256, 0, stream>>>(Qb, Kb, Vb, AO);
        gemm_xwt<0><<<512, 256, 0, stream>>>(AO, Wo, bo, out);
    }
}